// Round 1
// baseline (333.060 us; speedup 1.0000x reference)
//
#include <hip/hip_runtime.h>
#include <hip/hip_bf16.h>
#include <math.h>

// ---------- types ----------
typedef __attribute__((ext_vector_type(8))) short bf16x8;   // 8 bf16 in 4 VGPRs
typedef __attribute__((ext_vector_type(4))) float f32x4;

// ---------- helpers ----------
__device__ __forceinline__ unsigned short f2bf_rne(float f) {
    union { float f; unsigned u; } x; x.f = f;
    unsigned r = x.u + 0x7FFFu + ((x.u >> 16) & 1u);
    return (unsigned short)(r >> 16);
}

// 4 consecutive elements per lane (transposed-MFMA epilogue): 8B bf16 / 16B f32
__device__ __forceinline__ void store4(unsigned short* p, float v0, float v1, float v2, float v3) {
    ushort4 o; o.x = f2bf_rne(v0); o.y = f2bf_rne(v1); o.z = f2bf_rne(v2); o.w = f2bf_rne(v3);
    *(ushort4*)p = o;          // 8 B store, gn0 % 4 == 0 -> aligned
}
__device__ __forceinline__ void store4(float* p, float v0, float v1, float v2, float v3) {
    float4 o; o.x = v0; o.y = v1; o.z = v2; o.w = v3;
    *(float4*)p = o;           // 16 B store
}

__device__ __forceinline__ void async_copy16(const void* g, void* l) {
    __builtin_amdgcn_global_load_lds(
        (const __attribute__((address_space(1))) void*)g,
        (__attribute__((address_space(3))) void*)l, 16, 0, 0);
}

// ---------- fused fp32 -> bf16 converts + rowsum zeroing (one launch) ----------
__global__ __launch_bounds__(256) void cvt_all(
    const float* __restrict__ x,  const float* __restrict__ wq, const float* __restrict__ wo,
    unsigned short* __restrict__ xb, unsigned short* __restrict__ wqb, unsigned short* __restrict__ wob,
    float* __restrict__ rsum,
    int n4x, int n4q, int n4o, int n4r)
{
    int j = blockIdx.x * 256 + threadIdx.x;
    const float* in; unsigned short* out;
    if (j < n4x) { in = x; out = xb; }
    else {
        j -= n4x;
        if (j < n4q) { in = wq; out = wqb; }
        else {
            j -= n4q;
            if (j < n4o) { in = wo; out = wob; }
            else {
                j -= n4o;
                if (j < n4r) { float4 z = {0.f, 0.f, 0.f, 0.f}; ((float4*)rsum)[j] = z; }
                return;
            }
        }
    }
    float4 v = ((const float4*)in)[j];
    ushort4 o;
    o.x = f2bf_rne(v.x); o.y = f2bf_rne(v.y);
    o.z = f2bf_rne(v.z); o.w = f2bf_rne(v.w);
    ((ushort4*)out)[j] = o;
}

// ---------- NT bf16 GEMM: C[m,n] = f( scale * sum_k A[m,k]*B[n,k] ) + bias[n] ----------
// 256x256 tile, BK=64, 512 threads = 8 waves (2M x 4N), 128x64 output per wave,
// 8x4 MFMA 16x16x32 fragments per wave, 8-phase (4 phases/K-tile) schedule:
//   per phase: {ds_read subtile || issue 1 half-tile global_load_lds} -> barrier ->
//              lgkmcnt(0) -> setprio(1) 16 MFMA setprio(0) -> barrier
// Counted vmcnt(6) ONCE per K-tile (phase 4) — never vmcnt(0) in the main loop:
// 3 half-tiles stay in flight across barriers (T3+T4). Double-buffered LDS 128 KiB.
// Half-tile units are per-wave-half so the single gate covers every wave's reads:
//   A0 = LDS rows {0..63,128..191}  (m-half0 of both wave rows), A1 = complement
//   B0 = rows {wn*64 .. wn*64+31}   (n-half0 of each wave col),  B1 = complement
// Issue order: ...A0(T),B0(T),B1(T) during T-2/T-1; A1(T) at (T-1).P1. Gate at
// (T-1).P4 vmcnt(6) retires everything except {A0,B0,B1}(T+1) -> all tile-T data
// visible after the following barrier. T+2 units overwrite the current buffer's
// already-consumed regions (each region's last LDS read completes >=1 barrier
// before the overwriting issue). Tail tiles clamp K-offset (harmless re-stage).
// LDS XOR-swizzled in 16B granules (conflict-free, verified: SQ_LDS_BANK_CONFLICT=0).
// MFMA operands SWAPPED (D = B-frag x A-frag = C^T fragment) -> contiguous 8B/16B stores.
//
// Epilogue fusions:
//   DO_EXP:    store exp(scale*acc), atomicAdd per-row partials into rowsum[]
//   DO_RSCALE: multiply row m by 1/rowsum[m]
//   DO_VT:     blocks with tileN >= 1536 write vt[b][d][k] transposed
template <typename OutT, bool DO_EXP, bool DO_RSCALE, bool DO_VT>
__global__ __launch_bounds__(512) void gemm_nt_bf16(
    const unsigned short* __restrict__ A, int lda, long long strideA,
    const unsigned short* __restrict__ B, int ldb, long long strideB,
    OutT* __restrict__ C, int ldc, long long strideC,
    const float* __restrict__ bias, float scale, int K,
    float* __restrict__ rowsum, const float* __restrict__ rscale,
    unsigned short* __restrict__ vtp)
{
    __shared__ unsigned short shA[2 * 256 * 64];   // 64 KiB, [parity][row 0..255][k 0..63]
    __shared__ unsigned short shB[2 * 256 * 64];   // 64 KiB

    const int t    = threadIdx.x;
    const int lane = t & 63;
    const int wave = t >> 6;            // 0..7
    const int wm128 = (wave & 1) << 7;  // wave row offset in tile (0/128)
    const int wn64  = (wave >> 1) << 6; // wave col offset in tile (0/64/128/192)
    const int quad = lane >> 4;
    const int l16  = lane & 15;

    const long long batch = blockIdx.z;
    A += batch * strideA;
    B += batch * strideB;
    C += batch * strideC;

    const long long tileM = (long long)blockIdx.y * 256;
    const long long tileN = (long long)blockIdx.x * 256;
    const long long rowsPerBatch = (long long)gridDim.y * 256;

    // ---- staging per-thread constants (dest is lane-linear: base + lane*16B) ----
    const int dA   = t << 3;                                  // A dest (elems): rows t>>3 (+128*l, +64*ha)
    const int lrB0 = ((t >> 3) & 31) + ((t >> 8) << 6);       // B base row (+128*l, +32*hb)
    const int dB   = lrB0 * 64 + ((t & 7) << 3);
    const int cs   = (((t & 7) ^ ((t >> 3) & 7)) << 3);       // swizzled source k-offset (elems)
    const long long lda64  = (long long)lda * 64,  lda128 = lda64 * 2;
    const long long ldb32  = (long long)ldb * 32,  ldb128 = ldb32 * 4;
    const unsigned short* const Asrc = A + (tileM + (t >> 3)) * (long long)lda + cs;
    const unsigned short* const Bsrc = B + (tileN + lrB0) * (long long)ldb + cs;

#define STAGE_A(kOff, shp, ha) do {                                                      \
        async_copy16(Asrc + (ha) * lda64 + (kOff),          (shp) + dA + (ha) * 4096);   \
        async_copy16(Asrc + lda128 + (ha) * lda64 + (kOff), (shp) + dA + 8192 + (ha) * 4096); \
    } while (0)
#define STAGE_B(kOff, shp, hb) do {                                                      \
        async_copy16(Bsrc + (hb) * ldb32 + (kOff),          (shp) + dB + (hb) * 2048);   \
        async_copy16(Bsrc + ldb128 + (hb) * ldb32 + (kOff), (shp) + dB + 8192 + (hb) * 2048); \
    } while (0)

    bf16x8 a_[4][2], b_[4][2];

#define READ_A(shp, mh) do {                                                             \
        _Pragma("unroll")                                                                \
        for (int mi = 0; mi < 4; ++mi) {                                                 \
            const int row_ = wm128 + (mh) * 64 + mi * 16 + l16;                          \
            _Pragma("unroll")                                                            \
            for (int h = 0; h < 2; ++h) {                                                \
                const int kg_ = ((h << 2) | quad) ^ (row_ & 7);                          \
                a_[mi][h] = *(const bf16x8*)&(shp)[row_ * 64 + (kg_ << 3)];              \
            } } } while (0)
#define READ_B(shp, nh) do {                                                             \
        _Pragma("unroll")                                                                \
        for (int ni = 0; ni < 2; ++ni) {                                                 \
            const int row_ = wn64 + (nh) * 32 + ni * 16 + l16;                           \
            _Pragma("unroll")                                                            \
            for (int h = 0; h < 2; ++h) {                                                \
                const int kg_ = ((h << 2) | quad) ^ (row_ & 7);                          \
                b_[(nh) * 2 + ni][h] = *(const bf16x8*)&(shp)[row_ * 64 + (kg_ << 3)];   \
            } } } while (0)
#define MFMA_Q(mh, nh) do {                                                              \
        __builtin_amdgcn_s_setprio(1);                                                   \
        _Pragma("unroll")                                                                \
        for (int mi = 0; mi < 4; ++mi)                                                   \
            _Pragma("unroll")                                                            \
            for (int nj = 0; nj < 2; ++nj)                                               \
                _Pragma("unroll")                                                        \
                for (int h = 0; h < 2; ++h)                                              \
                    acc[(mh) * 4 + mi][(nh) * 2 + nj] =                                  \
                        __builtin_amdgcn_mfma_f32_16x16x32_bf16(                         \
                            b_[(nh) * 2 + nj][h], a_[mi][h],                             \
                            acc[(mh) * 4 + mi][(nh) * 2 + nj], 0, 0, 0);                 \
        __builtin_amdgcn_s_setprio(0);                                                   \
    } while (0)
#define LGKM0() do { asm volatile("s_waitcnt lgkmcnt(0)" ::: "memory");                  \
                     __builtin_amdgcn_sched_barrier(0); } while (0)

    f32x4 acc[8][4];
#pragma unroll
    for (int i = 0; i < 8; ++i)
#pragma unroll
        for (int j = 0; j < 4; ++j)
#pragma unroll
            for (int r = 0; r < 4; ++r) acc[i][j][r] = 0.0f;

    const int NT = K >> 6;   // >= 12 here

    // ---- prologue: tile0 {A0,B0,B1,A1} -> parity0; tile1 {A0,B0,B1} -> parity1 ----
    STAGE_A(0, shA, 0);
    STAGE_B(0, shB, 0);
    STAGE_B(0, shB, 1);
    STAGE_A(0, shA, 1);
    STAGE_A(64, shA + 16384, 0);
    STAGE_B(64, shB + 16384, 0);
    STAGE_B(64, shB + 16384, 1);
    asm volatile("s_waitcnt vmcnt(6)" ::: "memory");   // tile0 fully resident
    __builtin_amdgcn_s_barrier();

    for (int T = 0; T < NT; ++T) {
        const int cur = T & 1;
        unsigned short* const sAc = shA + cur * 16384;
        unsigned short* const sBc = shB + cur * 16384;
        unsigned short* const sAn = shA + (cur ^ 1) * 16384;
        const int k1 = ((T + 1 < NT) ? (T + 1) : (NT - 1)) * 64;  // A1(T+1)
        const int k2 = ((T + 2 < NT) ? (T + 2) : (NT - 1)) * 64;  // units of T+2

        // ---- P1: compute (m-half0, n-half0)
        READ_A(sAc, 0);                 // 8 x ds_read_b128
        READ_B(sBc, 0);                 // 4 x ds_read_b128
        STAGE_A(k1, sAn, 1);            // A1(T+1)
        __builtin_amdgcn_s_barrier();
        LGKM0();
        MFMA_Q(0, 0);
        __builtin_amdgcn_s_barrier();

        // ---- P2: compute (m-half0, n-half1)
        READ_B(sBc, 1);
        STAGE_A(k2, sAc, 0);            // A0(T+2) over consumed A0(T)
        __builtin_amdgcn_s_barrier();
        LGKM0();
        MFMA_Q(0, 1);
        __builtin_amdgcn_s_barrier();

        // ---- P3: compute (m-half1, n-half1)
        READ_A(sAc, 1);
        STAGE_B(k2, sBc, 0);            // B0(T+2) over consumed B0(T)
        __builtin_amdgcn_s_barrier();
        LGKM0();
        MFMA_Q(1, 1);
        __builtin_amdgcn_s_barrier();

        // ---- P4: compute (m-half1, n-half0)  [regs only: a_ from P3, b_[0..1] from P1]
        STAGE_B(k2, sBc, 1);            // B1(T+2) over consumed B1(T)
        asm volatile("s_waitcnt vmcnt(6)" ::: "memory");  // retire all of tile T+1
        __builtin_amdgcn_s_barrier();
        MFMA_Q(1, 0);
        __builtin_amdgcn_s_barrier();
    }
    asm volatile("s_waitcnt vmcnt(0)" ::: "memory");  // drain tail re-stages before endpgm

    // epilogue: D holds C^T tile: lane -> m = l16 (fixed row), n = quad*4 + {0..3}
    const bool vt_block = DO_VT && (tileN >= 1536);
#pragma unroll
    for (int mi = 0; mi < 8; ++mi) {
        const long long gm = tileM + wm128 + mi * 16 + l16;
        float w = scale;
        if (DO_RSCALE) w = scale / rscale[batch * rowsPerBatch + gm];
        float rsum = 0.0f;
#pragma unroll
        for (int ni = 0; ni < 4; ++ni) {
            const long long gn0 = tileN + wn64 + ni * 16 + quad * 4;
            float b0 = 0.f, b1 = 0.f, b2 = 0.f, b3 = 0.f;
            if (bias) {
                float4 bv = *(const float4*)&bias[gn0];
                b0 = bv.x; b1 = bv.y; b2 = bv.z; b3 = bv.w;
            }
            const f32x4 a = acc[mi][ni];
            float v0, v1, v2, v3;
            if (DO_EXP) {
                v0 = __expf(a[0] * scale); v1 = __expf(a[1] * scale);
                v2 = __expf(a[2] * scale); v3 = __expf(a[3] * scale);
                rsum += (v0 + v1) + (v2 + v3);
            } else {
                v0 = a[0] * w + b0; v1 = a[1] * w + b1;
                v2 = a[2] * w + b2; v3 = a[3] * w + b3;
            }
            if (vt_block) {
                // vt[b][d][k]: d = gn0-1536+r, b = gm>>10, k = gm&1023
                const long long b_   = gm >> 10;
                const long long kin  = gm & 1023;
                unsigned short* vp = vtp + (b_ * 768 + (gn0 - 1536)) * 1024 + kin;
                vp[0]        = f2bf_rne(v0);
                vp[1024]     = f2bf_rne(v1);
                vp[2 * 1024] = f2bf_rne(v2);
                vp[3 * 1024] = f2bf_rne(v3);
            } else {
                store4(C + gm * (long long)ldc + gn0, v0, v1, v2, v3);
            }
        }
        if (DO_EXP) {
            // lanes sharing l16 (quad bits = lane bits 4,5) hold disjoint n-ranges
            rsum += __shfl_xor(rsum, 16);
            rsum += __shfl_xor(rsum, 32);
            if (quad == 0)
                atomicAdd(&rowsum[batch * rowsPerBatch + gm], rsum);
        }
    }
#undef STAGE_A
#undef STAGE_B
#undef READ_A
#undef READ_B
#undef MFMA_Q
#undef LGKM0
}

// ---------- launcher ----------
extern "C" void kernel_launch(void* const* d_in, const int* in_sizes, int n_in,
                              void* d_out, int out_size, void* d_ws, size_t ws_size,
                              hipStream_t stream) {
    (void)in_sizes; (void)n_in; (void)out_size; (void)ws_size;

    const float* x     = (const float*)d_in[0];
    const float* w_qkv = (const float*)d_in[1];
    const float* b_qkv = (const float*)d_in[2];
    const float* w_out = (const float*)d_in[3];
    const float* b_out = (const float*)d_in[4];
    float* out = (float*)d_out;

    const int B = 16, S = 1024, D = 768;
    const long long MS = (long long)B * S;  // 16384 rows

    // workspace layout (bf16 = ushort), all 16B aligned
    unsigned short* xb   = (unsigned short*)d_ws;          // [16384][768]
    unsigned short* wqb  = xb   + MS * D;                  // [2304][768]
    unsigned short* wob  = wqb  + 3LL * D * D;             // [768][768]
    unsigned short* qkvb = wob  + (long long)D * D;        // [16384][2304] (V third unused)
    unsigned short* att  = qkvb + MS * 3 * D;              // [16][1024][1024] exp(logits)
    unsigned short* vt   = att  + (long long)B * S * S;    // [16][768][1024]
    unsigned short* ob   = vt   + (long long)B * D * S;    // [16384][768]
    float*          rsum = (float*)(ob + MS * D);          // [16][1024]

    // 1) converts + rowsum zeroing (single launch)
    {
        const int n4x = (int)(MS * D / 4);
        const int n4q = 3 * D * D / 4;
        const int n4o = D * D / 4;
        const int n4r = B * S / 4;
        const int tot = n4x + n4q + n4o + n4r;
        cvt_all<<<(tot + 255) / 256, 256, 0, stream>>>(x, w_qkv, w_out, xb, wqb, wob,
                                                      rsum, n4x, n4q, n4o, n4r);
    }

    // 2) QKV = x @ Wqkv^T + b  [16384, 2304]; V third written TRANSPOSED to vt
    gemm_nt_bf16<unsigned short, false, false, true><<<dim3(3 * D / 256, MS / 256, 1), 512, 0, stream>>>(
        xb, D, 0, wqb, D, 0, qkvb, 3 * D, 0, b_qkv, 1.0f, D, nullptr, nullptr, vt);

    // 3) att = exp(scale * Q @ K^T) per batch [1024,1024]; rowsum via atomics
    const float scale = 0.03608439182435162f;  // 1/sqrt(768)
    gemm_nt_bf16<unsigned short, true, false, false><<<dim3(S / 256, S / 256, B), 512, 0, stream>>>(
        qkvb,     3 * D, (long long)S * 3 * D,
        qkvb + D, 3 * D, (long long)S * 3 * D,
        att, S, (long long)S * S, nullptr, scale, D, rsum, nullptr, nullptr);

    // 4) O = (P~ @ V) * 1/rowsum per row   per batch [1024, 768]
    gemm_nt_bf16<unsigned short, false, true, false><<<dim3(D / 256, S / 256, B), 512, 0, stream>>>(
        att, S, (long long)S * S,
        vt,  S, (long long)D * S,
        ob,  D, (long long)S * D, nullptr, 1.0f, S, nullptr, rsum, nullptr);

    // 5) out = O @ Wout^T + b   [16384, 768] fp32
    gemm_nt_bf16<float, false, false, false><<<dim3(D / 256, MS / 256, 1), 512, 0, stream>>>(
        ob, D, 0, wob, D, 0, out, D, 0, b_out, 1.0f, D, nullptr, nullptr, nullptr);
}

// Round 2
// 324.020 us; speedup vs baseline: 1.0279x; 1.0279x over previous
//
#include <hip/hip_runtime.h>
#include <hip/hip_bf16.h>
#include <math.h>

// ---------- types ----------
typedef __attribute__((ext_vector_type(8))) short bf16x8;   // 8 bf16 in 4 VGPRs
typedef __attribute__((ext_vector_type(4))) float f32x4;

// ---------- helpers ----------
__device__ __forceinline__ unsigned short f2bf_rne(float f) {
    union { float f; unsigned u; } x; x.f = f;
    unsigned r = x.u + 0x7FFFu + ((x.u >> 16) & 1u);
    return (unsigned short)(r >> 16);
}

// 4 consecutive elements per lane (transposed-MFMA epilogue): 8B bf16 / 16B f32
__device__ __forceinline__ void store4(unsigned short* p, float v0, float v1, float v2, float v3) {
    ushort4 o; o.x = f2bf_rne(v0); o.y = f2bf_rne(v1); o.z = f2bf_rne(v2); o.w = f2bf_rne(v3);
    *(ushort4*)p = o;          // 8 B store, gn0 % 4 == 0 -> aligned
}
__device__ __forceinline__ void store4(float* p, float v0, float v1, float v2, float v3) {
    float4 o; o.x = v0; o.y = v1; o.z = v2; o.w = v3;
    *(float4*)p = o;           // 16 B store
}

__device__ __forceinline__ void async_copy16(const void* g, void* l) {
    __builtin_amdgcn_global_load_lds(
        (const __attribute__((address_space(1))) void*)g,
        (__attribute__((address_space(3))) void*)l, 16, 0, 0);
}

// ---------- fused fp32 -> bf16 converts + rowsum zeroing (one launch) ----------
__global__ __launch_bounds__(256) void cvt_all(
    const float* __restrict__ x,  const float* __restrict__ wq, const float* __restrict__ wo,
    unsigned short* __restrict__ xb, unsigned short* __restrict__ wqb, unsigned short* __restrict__ wob,
    float* __restrict__ rsum,
    int n4x, int n4q, int n4o, int n4r)
{
    int j = blockIdx.x * 256 + threadIdx.x;
    const float* in; unsigned short* out;
    if (j < n4x) { in = x; out = xb; }
    else {
        j -= n4x;
        if (j < n4q) { in = wq; out = wqb; }
        else {
            j -= n4q;
            if (j < n4o) { in = wo; out = wob; }
            else {
                j -= n4o;
                if (j < n4r) { float4 z = {0.f, 0.f, 0.f, 0.f}; ((float4*)rsum)[j] = z; }
                return;
            }
        }
    }
    float4 v = ((const float4*)in)[j];
    ushort4 o;
    o.x = f2bf_rne(v.x); o.y = f2bf_rne(v.y);
    o.z = f2bf_rne(v.z); o.w = f2bf_rne(v.w);
    ((ushort4*)out)[j] = o;
}

// ---------- NT bf16 GEMM: C[m,n] = f( scale * sum_k A[m,k]*B[n,k] ) + bias[n] ----------
// 256x256 tile, BK=64, 512 threads = 8 waves (2M x 4N), 128x64 output per wave.
// 8-phase schedule over TWO K-tiles per loop iteration (STATIC parity!):
// LDS is split into 8 SEPARATE 16 KiB __shared__ arrays (A-half x B-half x parity).
// Rationale (R1 post-mortem): with one big array + runtime parity, LLVM's waitcnt
// legalizer treats every ds_read as may-aliasing the latest global_load_lds and
// inserts per-phase vmcnt(0) drains -> "8-phase with drain-0" = slower than the
// 2-barrier baseline. Static distinct arrays make all auto-waits large-N counted
// (free); correctness is carried by the two explicit vmcnt(6) gates (P4/P8).
// No asm lgkmcnt / sched_barrier: ds_reads are plain loads, compiler emits
// fine-grained lgkmcnt waits before the dependent MFMAs (m141 lesson).
//
// Half-tile units (16 KiB each, 2 global_load_lds/thread):
//   A_h: local row L in [0,128) -> global row tileM + (L>>6)*128 + h*64 + (L&63)
//   B_h: local row L in [0,128) -> global row tileN + (L>>5)*64  + h*32 + (L&31)
// Issue order (steady state), 1 unit/phase:
//   P1:A1b(T+1) P2:A0a(T+2) P3:B0a(T+2) P4:B1a(T+2) [gate vmcnt(6): T+1 resident]
//   P5:A1a(T+2) P6:A0b(T+3) P7:B0b(T+3) P8:B1b(T+3) [gate vmcnt(6): T+2 resident]
// Stage-over-read hazards are barrier-separated WAR; tail clamps re-stage the
// last tile (value-identical, never consumed).
// LDS XOR-swizzled in 16B granules keyed on local row (conflict-free).
// MFMA operands SWAPPED (D = B-frag x A-frag = C^T fragment) -> contiguous stores.
//
// Epilogue fusions:
//   DO_EXP:    store exp(scale*acc), atomicAdd per-row partials into rowsum[]
//   DO_RSCALE: multiply row m by 1/rowsum[m]
//   DO_VT:     blocks with tileN >= 1536 write vt[b][d][k] transposed
template <typename OutT, bool DO_EXP, bool DO_RSCALE, bool DO_VT>
__global__ __launch_bounds__(512) void gemm_nt_bf16(
    const unsigned short* __restrict__ A, int lda, long long strideA,
    const unsigned short* __restrict__ B, int ldb, long long strideB,
    OutT* __restrict__ C, int ldc, long long strideC,
    const float* __restrict__ bias, float scale, int K,
    float* __restrict__ rowsum, const float* __restrict__ rscale,
    unsigned short* __restrict__ vtp)
{
    // 8 x 16 KiB = 128 KiB. Separate objects -> NoAlias for the waitcnt legalizer.
    __shared__ unsigned short A0a[128 * 64], A1a[128 * 64], B0a[128 * 64], B1a[128 * 64];
    __shared__ unsigned short A0b[128 * 64], A1b[128 * 64], B0b[128 * 64], B1b[128 * 64];

    const int t    = threadIdx.x;
    const int lane = t & 63;
    const int wave = t >> 6;            // 0..7
    const int wm128 = (wave & 1) << 7;  // wave row offset in tile (0/128)
    const int wn64  = (wave >> 1) << 6; // wave col offset in tile (0/64/128/192)
    const int quad = lane >> 4;
    const int l16  = lane & 15;
    const int wmL  = (wave & 1) << 6;   // local row base for A reads (0/64)
    const int wnL  = (wave >> 1) << 5;  // local row base for B reads (0/32/64/96)

    const long long batch = blockIdx.z;
    A += batch * strideA;
    B += batch * strideB;
    C += batch * strideC;

    const long long tileM = (long long)blockIdx.y * 256;
    const long long tileN = (long long)blockIdx.x * 256;
    const long long rowsPerBatch = (long long)gridDim.y * 256;

    // ---- staging per-thread constants (dest is lane-linear: base + lane*16B) ----
    const int dD   = t << 3;                                  // dest elem offset, copy0
    const int lrB0 = ((t >> 3) & 31) + ((t >> 8) << 6);       // B base row
    const int cs   = (((t & 7) ^ ((t >> 3) & 7)) << 3);       // swizzled source k-offset (elems)
    const long long lda64  = (long long)lda * 64,  lda128 = lda64 * 2;
    const long long ldb32  = (long long)ldb * 32,  ldb128 = ldb32 * 4;
    const unsigned short* const Asrc = A + (tileM + (t >> 3)) * (long long)lda + cs;
    const unsigned short* const Bsrc = B + (tileN + lrB0) * (long long)ldb + cs;

#define STAGE_A(kOff, arr, h) do {                                                       \
        async_copy16(Asrc + (h) * lda64 + (kOff),          (arr) + dD);                  \
        async_copy16(Asrc + lda128 + (h) * lda64 + (kOff), (arr) + 4096 + dD);           \
    } while (0)
#define STAGE_B(kOff, arr, hb) do {                                                      \
        async_copy16(Bsrc + (hb) * ldb32 + (kOff),          (arr) + dD);                 \
        async_copy16(Bsrc + ldb128 + (hb) * ldb32 + (kOff), (arr) + 4096 + dD);          \
    } while (0)

    bf16x8 a_[4][2], b_[4][2];

#define READ_A(arr) do {                                                                 \
        _Pragma("unroll")                                                                \
        for (int mi = 0; mi < 4; ++mi) {                                                 \
            const int L_ = wmL + mi * 16 + l16;                                          \
            _Pragma("unroll")                                                            \
            for (int h = 0; h < 2; ++h) {                                                \
                const int kg_ = ((h << 2) | quad) ^ (L_ & 7);                            \
                a_[mi][h] = *(const bf16x8*)&(arr)[L_ * 64 + (kg_ << 3)];                 \
            } } } while (0)
#define READ_B(arr, nh) do {                                                             \
        _Pragma("unroll")                                                                \
        for (int ni = 0; ni < 2; ++ni) {                                                 \
            const int L_ = wnL + ni * 16 + l16;                                          \
            _Pragma("unroll")                                                            \
            for (int h = 0; h < 2; ++h) {                                                \
                const int kg_ = ((h << 2) | quad) ^ (L_ & 7);                            \
                b_[(nh) * 2 + ni][h] = *(const bf16x8*)&(arr)[L_ * 64 + (kg_ << 3)];      \
            } } } while (0)
#define MFMA_Q(mh, nh) do {                                                              \
        __builtin_amdgcn_s_setprio(1);                                                   \
        _Pragma("unroll")                                                                \
        for (int mi = 0; mi < 4; ++mi)                                                   \
            _Pragma("unroll")                                                            \
            for (int nj = 0; nj < 2; ++nj)                                               \
                _Pragma("unroll")                                                        \
                for (int h = 0; h < 2; ++h)                                              \
                    acc[(mh) * 4 + mi][(nh) * 2 + nj] =                                  \
                        __builtin_amdgcn_mfma_f32_16x16x32_bf16(                         \
                            b_[(nh) * 2 + nj][h], a_[mi][h],                             \
                            acc[(mh) * 4 + mi][(nh) * 2 + nj], 0, 0, 0);                 \
        __builtin_amdgcn_s_setprio(0);                                                   \
    } while (0)
#define BAR() __builtin_amdgcn_s_barrier()
#define GATE6() asm volatile("s_waitcnt vmcnt(6)" ::: "memory")

    f32x4 acc[8][4];
#pragma unroll
    for (int i = 0; i < 8; ++i)
#pragma unroll
        for (int j = 0; j < 4; ++j)
#pragma unroll
            for (int r = 0; r < 4; ++r) acc[i][j][r] = 0.0f;

    const int NT = K >> 6;   // 12 or 16 here — always even

    // ---- prologue: tile0 {A0a,B0a,B1a,A1a}; tile1 {A0b,B0b,B1b} ----
    STAGE_A(0, A0a, 0);
    STAGE_B(0, B0a, 0);
    STAGE_B(0, B1a, 1);
    STAGE_A(0, A1a, 1);
    STAGE_A(64, A0b, 0);
    STAGE_B(64, B0b, 0);
    STAGE_B(64, B1b, 1);
    GATE6();                 // tile0 fully resident (newest 3 units = tile1)
    BAR();

    for (int T = 0; T < NT; T += 2) {
        const int k1 = (T + 1) * 64;                            // always valid
        const int k2 = ((T + 2 < NT) ? (T + 2) : (NT - 1)) * 64;
        const int k3 = ((T + 3 < NT) ? (T + 3) : (NT - 1)) * 64;

        // ===== tile T (parity a) =====
        // P1: (m0,n0)
        READ_A(A0a);
        READ_B(B0a, 0);
        STAGE_A(k1, A1b, 1);            // A1(T+1)
        BAR();
        MFMA_Q(0, 0);
        BAR();
        // P2: (m0,n1)
        READ_B(B1a, 1);
        STAGE_A(k2, A0a, 0);            // A0(T+2) over consumed A0(T)
        BAR();
        MFMA_Q(0, 1);
        BAR();
        // P3: (m1,n1)
        READ_A(A1a);
        STAGE_B(k2, B0a, 0);            // B0(T+2)
        BAR();
        MFMA_Q(1, 1);
        BAR();
        // P4: (m1,n0) — regs only
        STAGE_B(k2, B1a, 1);            // B1(T+2)
        GATE6();                        // retire all of tile T+1
        BAR();
        MFMA_Q(1, 0);
        BAR();

        // ===== tile T+1 (parity b) =====
        // P5: (m0,n0)
        READ_A(A0b);
        READ_B(B0b, 0);
        STAGE_A(k2, A1a, 1);            // A1(T+2)
        BAR();
        MFMA_Q(0, 0);
        BAR();
        // P6: (m0,n1)
        READ_B(B1b, 1);
        STAGE_A(k3, A0b, 0);            // A0(T+3)
        BAR();
        MFMA_Q(0, 1);
        BAR();
        // P7: (m1,n1)
        READ_A(A1b);
        STAGE_B(k3, B0b, 0);            // B0(T+3)
        BAR();
        MFMA_Q(1, 1);
        BAR();
        // P8: (m1,n0) — regs only
        STAGE_B(k3, B1b, 1);            // B1(T+3)
        GATE6();                        // retire all of tile T+2
        BAR();
        MFMA_Q(1, 0);
        BAR();
    }
    asm volatile("s_waitcnt vmcnt(0)" ::: "memory");  // drain tail re-stages

    // epilogue: D holds C^T tile: lane -> m = l16 (fixed row), n = quad*4 + {0..3}
    const bool vt_block = DO_VT && (tileN >= 1536);
#pragma unroll
    for (int mi = 0; mi < 8; ++mi) {
        const long long gm = tileM + wm128 + mi * 16 + l16;
        float w = scale;
        if (DO_RSCALE) w = scale / rscale[batch * rowsPerBatch + gm];
        float rsum = 0.0f;
#pragma unroll
        for (int ni = 0; ni < 4; ++ni) {
            const long long gn0 = tileN + wn64 + ni * 16 + quad * 4;
            float b0 = 0.f, b1 = 0.f, b2 = 0.f, b3 = 0.f;
            if (bias) {
                float4 bv = *(const float4*)&bias[gn0];
                b0 = bv.x; b1 = bv.y; b2 = bv.z; b3 = bv.w;
            }
            const f32x4 a = acc[mi][ni];
            float v0, v1, v2, v3;
            if (DO_EXP) {
                v0 = __expf(a[0] * scale); v1 = __expf(a[1] * scale);
                v2 = __expf(a[2] * scale); v3 = __expf(a[3] * scale);
                rsum += (v0 + v1) + (v2 + v3);
            } else {
                v0 = a[0] * w + b0; v1 = a[1] * w + b1;
                v2 = a[2] * w + b2; v3 = a[3] * w + b3;
            }
            if (vt_block) {
                // vt[b][d][k]: d = gn0-1536+r, b = gm>>10, k = gm&1023
                const long long b_i  = gm >> 10;
                const long long kin  = gm & 1023;
                unsigned short* vp = vtp + (b_i * 768 + (gn0 - 1536)) * 1024 + kin;
                vp[0]        = f2bf_rne(v0);
                vp[1024]     = f2bf_rne(v1);
                vp[2 * 1024] = f2bf_rne(v2);
                vp[3 * 1024] = f2bf_rne(v3);
            } else {
                store4(C + gm * (long long)ldc + gn0, v0, v1, v2, v3);
            }
        }
        if (DO_EXP) {
            // lanes sharing l16 (quad bits = lane bits 4,5) hold disjoint n-ranges
            rsum += __shfl_xor(rsum, 16);
            rsum += __shfl_xor(rsum, 32);
            if (quad == 0)
                atomicAdd(&rowsum[batch * rowsPerBatch + gm], rsum);
        }
    }
#undef STAGE_A
#undef STAGE_B
#undef READ_A
#undef READ_B
#undef MFMA_Q
#undef BAR
#undef GATE6
}

// ---------- launcher ----------
extern "C" void kernel_launch(void* const* d_in, const int* in_sizes, int n_in,
                              void* d_out, int out_size, void* d_ws, size_t ws_size,
                              hipStream_t stream) {
    (void)in_sizes; (void)n_in; (void)out_size; (void)ws_size;

    const float* x     = (const float*)d_in[0];
    const float* w_qkv = (const float*)d_in[1];
    const float* b_qkv = (const float*)d_in[2];
    const float* w_out = (const float*)d_in[3];
    const float* b_out = (const float*)d_in[4];
    float* out = (float*)d_out;

    const int B = 16, S = 1024, D = 768;
    const long long MS = (long long)B * S;  // 16384 rows

    // workspace layout (bf16 = ushort), all 16B aligned
    unsigned short* xb   = (unsigned short*)d_ws;          // [16384][768]
    unsigned short* wqb  = xb   + MS * D;                  // [2304][768]
    unsigned short* wob  = wqb  + 3LL * D * D;             // [768][768]
    unsigned short* qkvb = wob  + (long long)D * D;        // [16384][2304] (V third unused)
    unsigned short* att  = qkvb + MS * 3 * D;              // [16][1024][1024] exp(logits)
    unsigned short* vt   = att  + (long long)B * S * S;    // [16][768][1024]
    unsigned short* ob   = vt   + (long long)B * D * S;    // [16384][768]
    float*          rsum = (float*)(ob + MS * D);          // [16][1024]

    // 1) converts + rowsum zeroing (single launch)
    {
        const int n4x = (int)(MS * D / 4);
        const int n4q = 3 * D * D / 4;
        const int n4o = D * D / 4;
        const int n4r = B * S / 4;
        const int tot = n4x + n4q + n4o + n4r;
        cvt_all<<<(tot + 255) / 256, 256, 0, stream>>>(x, w_qkv, w_out, xb, wqb, wob,
                                                      rsum, n4x, n4q, n4o, n4r);
    }

    // 2) QKV = x @ Wqkv^T + b  [16384, 2304]; V third written TRANSPOSED to vt
    gemm_nt_bf16<unsigned short, false, false, true><<<dim3(3 * D / 256, MS / 256, 1), 512, 0, stream>>>(
        xb, D, 0, wqb, D, 0, qkvb, 3 * D, 0, b_qkv, 1.0f, D, nullptr, nullptr, vt);

    // 3) att = exp(scale * Q @ K^T) per batch [1024,1024]; rowsum via atomics
    const float scale = 0.03608439182435162f;  // 1/sqrt(768)
    gemm_nt_bf16<unsigned short, true, false, false><<<dim3(S / 256, S / 256, B), 512, 0, stream>>>(
        qkvb,     3 * D, (long long)S * 3 * D,
        qkvb + D, 3 * D, (long long)S * 3 * D,
        att, S, (long long)S * S, nullptr, scale, D, rsum, nullptr, nullptr);

    // 4) O = (P~ @ V) * 1/rowsum per row   per batch [1024, 768]
    gemm_nt_bf16<unsigned short, false, true, false><<<dim3(D / 256, S / 256, B), 512, 0, stream>>>(
        att, S, (long long)S * S,
        vt,  S, (long long)D * S,
        ob,  D, (long long)S * D, nullptr, 1.0f, S, nullptr, rsum, nullptr);

    // 5) out = O @ Wout^T + b   [16384, 768] fp32
    gemm_nt_bf16<float, false, false, false><<<dim3(D / 256, MS / 256, 1), 512, 0, stream>>>(
        ob, D, 0, wob, D, 0, out, D, 0, b_out, 1.0f, D, nullptr, nullptr, nullptr);
}

// Round 3
// 315.193 us; speedup vs baseline: 1.0567x; 1.0280x over previous
//
#include <hip/hip_runtime.h>
#include <hip/hip_bf16.h>
#include <math.h>

// ---------- types ----------
typedef __attribute__((ext_vector_type(8))) short bf16x8;   // 8 bf16 in 4 VGPRs
typedef __attribute__((ext_vector_type(4))) float f32x4;

// ---------- helpers ----------
__device__ __forceinline__ unsigned short f2bf_rne(float f) {
    union { float f; unsigned u; } x; x.f = f;
    unsigned r = x.u + 0x7FFFu + ((x.u >> 16) & 1u);
    return (unsigned short)(r >> 16);
}

// 4 consecutive elements per lane (transposed-MFMA epilogue): 8B bf16 / 16B f32
__device__ __forceinline__ void store4(unsigned short* p, float v0, float v1, float v2, float v3) {
    ushort4 o; o.x = f2bf_rne(v0); o.y = f2bf_rne(v1); o.z = f2bf_rne(v2); o.w = f2bf_rne(v3);
    *(ushort4*)p = o;          // 8 B store, gn0 % 4 == 0 -> aligned
}
__device__ __forceinline__ void store4(float* p, float v0, float v1, float v2, float v3) {
    float4 o; o.x = v0; o.y = v1; o.z = v2; o.w = v3;
    *(float4*)p = o;           // 16 B store
}

__device__ __forceinline__ void async_copy16(const void* g, void* l) {
    __builtin_amdgcn_global_load_lds(
        (const __attribute__((address_space(1))) void*)g,
        (__attribute__((address_space(3))) void*)l, 16, 0, 0);
}

// ---------- fused fp32 -> bf16 converts + rowsum zeroing (one launch) ----------
__global__ __launch_bounds__(256) void cvt_all(
    const float* __restrict__ x,  const float* __restrict__ wq, const float* __restrict__ wo,
    unsigned short* __restrict__ xb, unsigned short* __restrict__ wqb, unsigned short* __restrict__ wob,
    float* __restrict__ rsum,
    int n4x, int n4q, int n4o, int n4r)
{
    int j = blockIdx.x * 256 + threadIdx.x;
    const float* in; unsigned short* out;
    if (j < n4x) { in = x; out = xb; }
    else {
        j -= n4x;
        if (j < n4q) { in = wq; out = wqb; }
        else {
            j -= n4q;
            if (j < n4o) { in = wo; out = wob; }
            else {
                j -= n4o;
                if (j < n4r) { float4 z = {0.f, 0.f, 0.f, 0.f}; ((float4*)rsum)[j] = z; }
                return;
            }
        }
    }
    float4 v = ((const float4*)in)[j];
    ushort4 o;
    o.x = f2bf_rne(v.x); o.y = f2bf_rne(v.y);
    o.z = f2bf_rne(v.z); o.w = f2bf_rne(v.w);
    ((ushort4*)out)[j] = o;
}

// ---------- NT bf16 GEMM: C[m,n] = f( scale * sum_k A[m,k]*B[n,k] ) + bias[n] ----------
// R0 geometry (proven): 128x128 tile, 256 threads = 4 waves (2x2), 64x64/wave,
// 4x4 MFMA 16x16x32 fragments. R3 changes ONLY the K-loop + block swizzle:
//
// K-loop: BK=32, depth-1 double-buffer (4 static 8 KiB __shared__ arrays, 32 KiB
// total -> ~3 blocks/CU preserved). Pattern per K-slice:
//   COMPUTE(cur); fence; s_barrier;          // all waves' reads retired (via MFMA)
//   STAGE(cur, slice+2);                     // 4 global_load_lds, overwrite consumed buf
//   s_waitcnt vmcnt(4); s_barrier;           // other parity's group resident (COUNTED)
// Rationale (R1/R2 post-mortems): deep global_load_lds pipelines overflow the
// compiler's LDS-DMA alias-tracking slots -> per-phase vmcnt(0) drains. Depth-1
// with exactly one outstanding stage-group at any ds_read stays tracked; static
// x2 unroll keeps buffer parity compile-time. Raw s_barrier (not __syncthreads)
// avoids the implicit vmcnt(0) drain. Tail K-slice-pair peeled (no clamps; gates
// stay exact: prologue vmcnt(4), tail vmcnt(0)).
// LDS swizzle for BK=32 (4 granules/row): pos = q ^ ((row>>1)&3) -> 2-way bank
// aliasing only (free, m136).
//
// XCD swizzle: grids all %8==0; linear block id remapped so each XCD gets a
// contiguous chunk -> per-batch QK^T/PV working sets (3-4 MB) become XCD-L2
// resident; staging latency L2-class instead of HBM-class.
//
// Epilogue fusions unchanged from R0:
//   DO_EXP:    store exp(scale*acc), atomicAdd per-row partials into rowsum[]
//   DO_RSCALE: multiply row m by 1/rowsum[m]
//   DO_VT:     blocks with tileN >= 1536 write vt[b][d][k] transposed
template <typename OutT, bool DO_EXP, bool DO_RSCALE, bool DO_VT>
__global__ __launch_bounds__(256) void gemm_nt_bf16(
    const unsigned short* __restrict__ A, int lda, long long strideA,
    const unsigned short* __restrict__ B, int ldb, long long strideB,
    OutT* __restrict__ C, int ldc, long long strideC,
    const float* __restrict__ bias, float scale, int K,
    float* __restrict__ rowsum, const float* __restrict__ rscale,
    unsigned short* __restrict__ vtp)
{
    // 4 x 8 KiB static buffers: [row 0..127][k 0..31], 16B-granule swizzled
    __shared__ unsigned short sA0[128 * 32], sB0[128 * 32];
    __shared__ unsigned short sA1[128 * 32], sB1[128 * 32];

    const int t    = threadIdx.x;
    const int lane = t & 63;
    const int wave = t >> 6;
    const int wm   = (wave & 1) * 64;   // wave row offset in tile
    const int wn   = (wave >> 1) * 64;  // wave col offset in tile
    const int quad = lane >> 4;
    const int l16  = lane & 15;

    // ---- XCD-chunked block swizzle (all launch grids are %8 == 0) ----
    const int gx = gridDim.x, gy = gridDim.y;
    const int nwg = gx * gy * gridDim.z;
    const int orig = blockIdx.x + gx * (blockIdx.y + gy * blockIdx.z);
    const int id  = (orig & 7) * (nwg >> 3) + (orig >> 3);
    const int bx  = id % gx;
    const int rem = id / gx;
    const int by  = rem % gy;
    const int bz  = rem / gy;

    const long long batch = bz;
    A += batch * strideA;
    B += batch * strideB;
    C += batch * strideC;

    const long long tileM = (long long)by * 128;
    const long long tileN = (long long)bx * 128;
    const long long rowsPerBatch = (long long)gy * 128;

    // ---- staging constants: thread t -> dest row t>>2 (copy0) / 64+(t>>2) (copy1),
    //      dest granule t&3; source k-granule = (t&3) ^ ((t>>3)&3) (same for both copies)
    const int cs = (((t & 3) ^ ((t >> 3) & 3)) << 3);          // swizzled source k elems
    const unsigned short* const Asrc = A + (tileM + (t >> 2)) * (long long)lda + cs;
    const unsigned short* const Bsrc = B + (tileN + (t >> 2)) * (long long)ldb + cs;
    const long long lda64 = (long long)lda * 64;
    const long long ldb64 = (long long)ldb * 64;
    const int dst0 = t << 3;            // elems
    const int dst1 = 2048 + (t << 3);   // rows 64..127

    // one stage-group = 4 wave-level global_load_lds -> gate is vmcnt(4)
#define STAGE(kOff, sAx, sBx) do {                                   \
        async_copy16(Asrc + (kOff),         (sAx) + dst0);           \
        async_copy16(Asrc + lda64 + (kOff), (sAx) + dst1);           \
        async_copy16(Bsrc + (kOff),         (sBx) + dst0);           \
        async_copy16(Bsrc + ldb64 + (kOff), (sBx) + dst1);           \
    } while (0)

#define COMPUTE(sAx, sBx) do {                                                           \
        bf16x8 af[4], bfr[4];                                                            \
        _Pragma("unroll")                                                                \
        for (int mi = 0; mi < 4; ++mi) {                                                 \
            const int row = wm + mi * 16 + l16;                                          \
            const int pos = quad ^ ((row >> 1) & 3);                                     \
            af[mi] = *(const bf16x8*)&(sAx)[row * 32 + (pos << 3)];                       \
        }                                                                                \
        _Pragma("unroll")                                                                \
        for (int ni = 0; ni < 4; ++ni) {                                                 \
            const int row = wn + ni * 16 + l16;                                          \
            const int pos = quad ^ ((row >> 1) & 3);                                     \
            bfr[ni] = *(const bf16x8*)&(sBx)[row * 32 + (pos << 3)];                      \
        }                                                                                \
        _Pragma("unroll")                                                                \
        for (int mi = 0; mi < 4; ++mi)                                                   \
            _Pragma("unroll")                                                            \
            for (int ni = 0; ni < 4; ++ni)                                               \
                acc[mi][ni] = __builtin_amdgcn_mfma_f32_16x16x32_bf16(                   \
                    bfr[ni], af[mi], acc[mi][ni], 0, 0, 0);  /* swapped: C^T frag */     \
    } while (0)

#define FENCE() asm volatile("" ::: "memory")
#define BAR()   __builtin_amdgcn_s_barrier()
#define GATE4() asm volatile("s_waitcnt vmcnt(4)" ::: "memory")
#define GATE0() asm volatile("s_waitcnt vmcnt(0)" ::: "memory")

    f32x4 acc[4][4];
#pragma unroll
    for (int i = 0; i < 4; ++i)
#pragma unroll
        for (int j = 0; j < 4; ++j)
#pragma unroll
            for (int r = 0; r < 4; ++r) acc[i][j][r] = 0.0f;

    const int NS = K >> 5;      // K-slices of 32 (24 or 32 here — always even)

    // ---- prologue: slices 0 -> parity0, 1 -> parity1 ----
    STAGE(0,  sA0, sB0);
    STAGE(32, sA1, sB1);
    GATE4();                    // slice0 resident (slice1's 4 loads still in flight)
    BAR();

    for (int it = 0; it < (NS >> 1) - 1; ++it) {
        const int k2 = (it * 2 + 2) << 5;
        const int k3 = (it * 2 + 3) << 5;
        // parity 0: compute slice 2it, restage slice 2it+2
        COMPUTE(sA0, sB0);
        FENCE(); BAR();         // all waves consumed parity0 -> safe to overwrite
        STAGE(k2, sA0, sB0);
        GATE4();                // parity1 group retired (counted: 4 newer in flight)
        BAR();
        // parity 1: compute slice 2it+1, restage slice 2it+3
        COMPUTE(sA1, sB1);
        FENCE(); BAR();
        STAGE(k3, sA1, sB1);
        GATE4();                // parity0 group retired
        BAR();
    }
    // ---- tail pair: slices NS-2, NS-1 (no staging, exact gates) ----
    COMPUTE(sA0, sB0);
    GATE0();                    // last parity1 group retired (all DMA done)
    BAR();
    COMPUTE(sA1, sB1);

    // epilogue: D holds C^T tile: lane -> m = l16 (fixed row), n = quad*4 + {0..3}
    const bool vt_block = DO_VT && (tileN >= 1536);
#pragma unroll
    for (int mi = 0; mi < 4; ++mi) {
        const long long gm = tileM + wm + mi * 16 + l16;
        float w = scale;
        if (DO_RSCALE) w = scale / rscale[batch * rowsPerBatch + gm];
        float rsum = 0.0f;
#pragma unroll
        for (int ni = 0; ni < 4; ++ni) {
            const long long gn0 = tileN + wn + ni * 16 + quad * 4;
            float b0 = 0.f, b1 = 0.f, b2 = 0.f, b3 = 0.f;
            if (bias) {
                float4 bv = *(const float4*)&bias[gn0];
                b0 = bv.x; b1 = bv.y; b2 = bv.z; b3 = bv.w;
            }
            const f32x4 a = acc[mi][ni];
            float v0, v1, v2, v3;
            if (DO_EXP) {
                v0 = __expf(a[0] * scale); v1 = __expf(a[1] * scale);
                v2 = __expf(a[2] * scale); v3 = __expf(a[3] * scale);
                rsum += (v0 + v1) + (v2 + v3);
            } else {
                v0 = a[0] * w + b0; v1 = a[1] * w + b1;
                v2 = a[2] * w + b2; v3 = a[3] * w + b3;
            }
            if (vt_block) {
                // vt[b][d][k]: d = gn0-1536+r, b = gm>>10, k = gm&1023
                const long long b_i  = gm >> 10;
                const long long kin  = gm & 1023;
                unsigned short* vp = vtp + (b_i * 768 + (gn0 - 1536)) * 1024 + kin;
                vp[0]        = f2bf_rne(v0);
                vp[1024]     = f2bf_rne(v1);
                vp[2 * 1024] = f2bf_rne(v2);
                vp[3 * 1024] = f2bf_rne(v3);
            } else {
                store4(C + gm * (long long)ldc + gn0, v0, v1, v2, v3);
            }
        }
        if (DO_EXP) {
            // lanes sharing l16 (quad bits = lane bits 4,5) hold disjoint n-ranges
            rsum += __shfl_xor(rsum, 16);
            rsum += __shfl_xor(rsum, 32);
            if (quad == 0)
                atomicAdd(&rowsum[batch * rowsPerBatch + gm], rsum);
        }
    }
#undef STAGE
#undef COMPUTE
#undef FENCE
#undef BAR
#undef GATE4
#undef GATE0
}

// ---------- launcher ----------
extern "C" void kernel_launch(void* const* d_in, const int* in_sizes, int n_in,
                              void* d_out, int out_size, void* d_ws, size_t ws_size,
                              hipStream_t stream) {
    (void)in_sizes; (void)n_in; (void)out_size; (void)ws_size;

    const float* x     = (const float*)d_in[0];
    const float* w_qkv = (const float*)d_in[1];
    const float* b_qkv = (const float*)d_in[2];
    const float* w_out = (const float*)d_in[3];
    const float* b_out = (const float*)d_in[4];
    float* out = (float*)d_out;

    const int B = 16, S = 1024, D = 768;
    const long long MS = (long long)B * S;  // 16384 rows

    // workspace layout (bf16 = ushort), all 16B aligned
    unsigned short* xb   = (unsigned short*)d_ws;          // [16384][768]
    unsigned short* wqb  = xb   + MS * D;                  // [2304][768]
    unsigned short* wob  = wqb  + 3LL * D * D;             // [768][768]
    unsigned short* qkvb = wob  + (long long)D * D;        // [16384][2304] (V third unused)
    unsigned short* att  = qkvb + MS * 3 * D;              // [16][1024][1024] exp(logits)
    unsigned short* vt   = att  + (long long)B * S * S;    // [16][768][1024]
    unsigned short* ob   = vt   + (long long)B * D * S;    // [16384][768]
    float*          rsum = (float*)(ob + MS * D);          // [16][1024]

    // 1) converts + rowsum zeroing (single launch)
    {
        const int n4x = (int)(MS * D / 4);
        const int n4q = 3 * D * D / 4;
        const int n4o = D * D / 4;
        const int n4r = B * S / 4;
        const int tot = n4x + n4q + n4o + n4r;
        cvt_all<<<(tot + 255) / 256, 256, 0, stream>>>(x, w_qkv, w_out, xb, wqb, wob,
                                                      rsum, n4x, n4q, n4o, n4r);
    }

    // 2) QKV = x @ Wqkv^T + b  [16384, 2304]; V third written TRANSPOSED to vt
    gemm_nt_bf16<unsigned short, false, false, true><<<dim3(3 * D / 128, MS / 128, 1), 256, 0, stream>>>(
        xb, D, 0, wqb, D, 0, qkvb, 3 * D, 0, b_qkv, 1.0f, D, nullptr, nullptr, vt);

    // 3) att = exp(scale * Q @ K^T) per batch [1024,1024]; rowsum via atomics
    const float scale = 0.03608439182435162f;  // 1/sqrt(768)
    gemm_nt_bf16<unsigned short, true, false, false><<<dim3(S / 128, S / 128, B), 256, 0, stream>>>(
        qkvb,     3 * D, (long long)S * 3 * D,
        qkvb + D, 3 * D, (long long)S * 3 * D,
        att, S, (long long)S * S, nullptr, scale, D, rsum, nullptr, nullptr);

    // 4) O = (P~ @ V) * 1/rowsum per row   per batch [1024, 768]
    gemm_nt_bf16<unsigned short, false, true, false><<<dim3(D / 128, S / 128, B), 256, 0, stream>>>(
        att, S, (long long)S * S,
        vt,  S, (long long)D * S,
        ob,  D, (long long)S * D, nullptr, 1.0f, S, nullptr, rsum, nullptr);

    // 5) out = O @ Wout^T + b   [16384, 768] fp32
    gemm_nt_bf16<float, false, false, false><<<dim3(D / 128, MS / 128, 1), 256, 0, stream>>>(
        ob, D, 0, wob, D, 0, out, D, 0, b_out, 1.0f, D, nullptr, nullptr, nullptr);
}

// Round 4
// 293.680 us; speedup vs baseline: 1.1341x; 1.0733x over previous
//
#include <hip/hip_runtime.h>
#include <hip/hip_bf16.h>
#include <math.h>

// ---------- types ----------
typedef __attribute__((ext_vector_type(8))) short bf16x8;   // 8 bf16 in 4 VGPRs
typedef __attribute__((ext_vector_type(4))) float f32x4;

// ---------- helpers ----------
__device__ __forceinline__ unsigned short f2bf_rne(float f) {
    union { float f; unsigned u; } x; x.f = f;
    unsigned r = x.u + 0x7FFFu + ((x.u >> 16) & 1u);
    return (unsigned short)(r >> 16);
}

// 4 consecutive elements per lane (transposed-MFMA epilogue): 8B bf16 / 16B f32
__device__ __forceinline__ void store4(unsigned short* p, float v0, float v1, float v2, float v3) {
    ushort4 o; o.x = f2bf_rne(v0); o.y = f2bf_rne(v1); o.z = f2bf_rne(v2); o.w = f2bf_rne(v3);
    *(ushort4*)p = o;          // 8 B store, gn0 % 4 == 0 -> aligned
}
__device__ __forceinline__ void store4(float* p, float v0, float v1, float v2, float v3) {
    float4 o; o.x = v0; o.y = v1; o.z = v2; o.w = v3;
    *(float4*)p = o;           // 16 B store
}

__device__ __forceinline__ void async_copy16(const void* g, void* l) {
    __builtin_amdgcn_global_load_lds(
        (const __attribute__((address_space(1))) void*)g,
        (__attribute__((address_space(3))) void*)l, 16, 0, 0);
}

// ---------- fused fp32 -> bf16 converts + rowsum zeroing (one launch) ----------
__global__ __launch_bounds__(256) void cvt_all(
    const float* __restrict__ x,  const float* __restrict__ wq, const float* __restrict__ wo,
    unsigned short* __restrict__ xb, unsigned short* __restrict__ wqb, unsigned short* __restrict__ wob,
    float* __restrict__ rsum,
    int n4x, int n4q, int n4o, int n4r)
{
    int j = blockIdx.x * 256 + threadIdx.x;
    const float* in; unsigned short* out;
    if (j < n4x) { in = x; out = xb; }
    else {
        j -= n4x;
        if (j < n4q) { in = wq; out = wqb; }
        else {
            j -= n4q;
            if (j < n4o) { in = wo; out = wob; }
            else {
                j -= n4o;
                if (j < n4r) { float4 z = {0.f, 0.f, 0.f, 0.f}; ((float4*)rsum)[j] = z; }
                return;
            }
        }
    }
    float4 v = ((const float4*)in)[j];
    ushort4 o;
    o.x = f2bf_rne(v.x); o.y = f2bf_rne(v.y);
    o.z = f2bf_rne(v.z); o.w = f2bf_rne(v.w);
    ((ushort4*)out)[j] = o;
}

// ---------- NT bf16 GEMM: C[m,n] = f( scale * sum_k A[m,k]*B[n,k] ) + bias[n] ----------
// R0-proven structure: 128x128 tile, BK=64, 256 threads = 4 waves (2x2), 64x64 per wave,
// 4x4 MFMA 16x16x32 tiles per wave, two K-halves per LDS stage.
// Staging: global_load_lds width=16, stage -> __syncthreads (drains) -> compute.
// R1-R3 post-mortems: every source-level async variant (8-phase counted vmcnt,
// 8 static LDS arrays, depth-1 BK=32 double-buffer) regressed to 518-617 TF vs
// this structure's 674 TF — the toolchain drains LDS-DMA at phase boundaries
// regardless of aliasing shape. Implicit wave-overlap at ~3 blocks/CU (32 KiB
// LDS, VGPR 72) is the best schedule reachable here. DO NOT re-add pipelining.
// LDS XOR-swizzled in 16B granules (conflict-free, verified: SQ_LDS_BANK_CONFLICT=0).
// MFMA operands SWAPPED (D = B-frag x A-frag = C^T fragment) -> contiguous 8B/16B stores.
//
// R3's one isolated win, kept: XCD-chunked block swizzle (all grids %8 == 0).
// Measured: QKV FETCH_SIZE 124 MB -> 64 MB (A/B-panel reuse becomes XCD-L2-hit);
// per-batch QK^T/PV working sets (3-4 MB) become XCD-L2 resident.
//
// Epilogue fusions:
//   DO_EXP:    store exp(scale*acc), atomicAdd per-row partials into rowsum[]
//              (logits ~N(0,1) -> no max-subtract needed; exact by shift-invariance).
//   DO_RSCALE: multiply row m by 1/rowsum[m]  (O = P~V then row-scale == softmax V).
//   DO_VT:     blocks with tileN >= 1536 (the V third of QKV output) write
//              vt[b][d][k] TRANSPOSED instead of C.
template <typename OutT, bool DO_EXP, bool DO_RSCALE, bool DO_VT>
__global__ __launch_bounds__(256) void gemm_nt_bf16(
    const unsigned short* __restrict__ A, int lda, long long strideA,
    const unsigned short* __restrict__ B, int ldb, long long strideB,
    OutT* __restrict__ C, int ldc, long long strideC,
    const float* __restrict__ bias, float scale, int K,
    float* __restrict__ rowsum, const float* __restrict__ rscale,
    unsigned short* __restrict__ vtp)
{
    __shared__ unsigned short shA[128 * 64];
    __shared__ unsigned short shB[128 * 64];

    const int t    = threadIdx.x;
    const int lane = t & 63;
    const int wave = t >> 6;
    const int wm   = (wave & 1) * 64;   // wave row offset in tile
    const int wn   = (wave >> 1) * 64;  // wave col offset in tile
    const int quad = lane >> 4;
    const int l16  = lane & 15;

    // ---- XCD-chunked block swizzle (all launch grids are %8 == 0) ----
    // HW round-robins linear workgroup id across 8 XCDs; remap so each XCD owns
    // a contiguous chunk of the (bx-fastest) tile space -> A/B panel reuse
    // within one XCD L2. Verified R3: QKV FETCH_SIZE halved.
    const int gx = gridDim.x, gy = gridDim.y;
    const int nwg = gx * gy * gridDim.z;
    const int orig = blockIdx.x + gx * (blockIdx.y + gy * blockIdx.z);
    const int id  = (orig & 7) * (nwg >> 3) + (orig >> 3);
    const int bx  = id % gx;
    const int rem = id / gx;
    const int by  = rem % gy;
    const int bz  = rem / gy;

    const long long batch = bz;
    A += batch * strideA;
    B += batch * strideB;
    C += batch * strideC;

    const long long tileM = (long long)by * 128;
    const long long tileN = (long long)bx * 128;
    const long long rowsPerBatch = (long long)gy * 128;

    f32x4 acc[4][4];
#pragma unroll
    for (int i = 0; i < 4; ++i)
#pragma unroll
        for (int j = 0; j < 4; ++j)
#pragma unroll
            for (int r = 0; r < 4; ++r) acc[i][j][r] = 0.0f;

    for (int k0 = 0; k0 < K; k0 += 64) {
        __syncthreads();   // previous iter's frags consumed before overwrite
#pragma unroll
        for (int p = 0; p < 4; ++p) {
            const int g   = p * 256 + t;        // LDS granule 0..1023 (lane-ordered)
            const int row = g >> 3;             // 0..127
            const int kg  = (g & 7) ^ (row & 7);// swizzled source k-granule
            async_copy16(A + (tileM + row) * (long long)lda + k0 + kg * 8, &shA[g << 3]);
            async_copy16(B + (tileN + row) * (long long)ldb + k0 + kg * 8, &shB[g << 3]);
        }
        __syncthreads();   // compiler drains vmcnt(0) before barrier

#pragma unroll 1           // keep only one K-half's fragments live (VGPR cap)
        for (int h = 0; h < 2; ++h) {
            bf16x8 af[4], bfr[4];
#pragma unroll
            for (int mi = 0; mi < 4; ++mi) {
                const int row = wm + mi * 16 + l16;
                const int kg  = ((h << 2) | quad) ^ (row & 7);
                af[mi] = *(const bf16x8*)(&shA[row * 64 + kg * 8]);
            }
#pragma unroll
            for (int ni = 0; ni < 4; ++ni) {
                const int row = wn + ni * 16 + l16;
                const int kg  = ((h << 2) | quad) ^ (row & 7);
                bfr[ni] = *(const bf16x8*)(&shB[row * 64 + kg * 8]);
            }
#pragma unroll
            for (int mi = 0; mi < 4; ++mi)
#pragma unroll
                for (int ni = 0; ni < 4; ++ni)
                    acc[mi][ni] = __builtin_amdgcn_mfma_f32_16x16x32_bf16(
                        bfr[ni], af[mi], acc[mi][ni], 0, 0, 0);   // operands swapped: D = C^T frag
        }
    }

    // epilogue: D holds C^T tile: lane -> m = l16 (fixed row), n = quad*4 + {0..3}
    const bool vt_block = DO_VT && (tileN >= 1536);
#pragma unroll
    for (int mi = 0; mi < 4; ++mi) {
        const long long gm = tileM + wm + mi * 16 + l16;
        float w = scale;
        if (DO_RSCALE) w = scale / rscale[batch * rowsPerBatch + gm];
        float rsum = 0.0f;
#pragma unroll
        for (int ni = 0; ni < 4; ++ni) {
            const long long gn0 = tileN + wn + ni * 16 + quad * 4;
            float b0 = 0.f, b1 = 0.f, b2 = 0.f, b3 = 0.f;
            if (bias) {
                float4 bv = *(const float4*)&bias[gn0];
                b0 = bv.x; b1 = bv.y; b2 = bv.z; b3 = bv.w;
            }
            const f32x4 a = acc[mi][ni];
            float v0, v1, v2, v3;
            if (DO_EXP) {
                v0 = __expf(a[0] * scale); v1 = __expf(a[1] * scale);
                v2 = __expf(a[2] * scale); v3 = __expf(a[3] * scale);
                rsum += (v0 + v1) + (v2 + v3);
            } else {
                v0 = a[0] * w + b0; v1 = a[1] * w + b1;
                v2 = a[2] * w + b2; v3 = a[3] * w + b3;
            }
            if (vt_block) {
                // vt[b][d][k]: d = gn0-1536+r, b = gm>>10, k = gm&1023
                const long long b_i  = gm >> 10;
                const long long kin  = gm & 1023;
                unsigned short* vp = vtp + (b_i * 768 + (gn0 - 1536)) * 1024 + kin;
                vp[0]        = f2bf_rne(v0);
                vp[1024]     = f2bf_rne(v1);
                vp[2 * 1024] = f2bf_rne(v2);
                vp[3 * 1024] = f2bf_rne(v3);
            } else {
                store4(C + gm * (long long)ldc + gn0, v0, v1, v2, v3);
            }
        }
        if (DO_EXP) {
            // lanes sharing l16 (quad bits = lane bits 4,5) hold disjoint n-ranges
            rsum += __shfl_xor(rsum, 16);
            rsum += __shfl_xor(rsum, 32);
            if (quad == 0)
                atomicAdd(&rowsum[batch * rowsPerBatch + gm], rsum);
        }
    }
}

// ---------- launcher ----------
extern "C" void kernel_launch(void* const* d_in, const int* in_sizes, int n_in,
                              void* d_out, int out_size, void* d_ws, size_t ws_size,
                              hipStream_t stream) {
    (void)in_sizes; (void)n_in; (void)out_size; (void)ws_size;

    const float* x     = (const float*)d_in[0];
    const float* w_qkv = (const float*)d_in[1];
    const float* b_qkv = (const float*)d_in[2];
    const float* w_out = (const float*)d_in[3];
    const float* b_out = (const float*)d_in[4];
    float* out = (float*)d_out;

    const int B = 16, S = 1024, D = 768;
    const long long MS = (long long)B * S;  // 16384 rows

    // workspace layout (bf16 = ushort), all 16B aligned
    unsigned short* xb   = (unsigned short*)d_ws;          // [16384][768]
    unsigned short* wqb  = xb   + MS * D;                  // [2304][768]
    unsigned short* wob  = wqb  + 3LL * D * D;             // [768][768]
    unsigned short* qkvb = wob  + (long long)D * D;        // [16384][2304] (V third unused)
    unsigned short* att  = qkvb + MS * 3 * D;              // [16][1024][1024] exp(logits)
    unsigned short* vt   = att  + (long long)B * S * S;    // [16][768][1024]
    unsigned short* ob   = vt   + (long long)B * D * S;    // [16384][768]
    float*          rsum = (float*)(ob + MS * D);          // [16][1024]

    // 1) converts + rowsum zeroing (single launch)
    {
        const int n4x = (int)(MS * D / 4);
        const int n4q = 3 * D * D / 4;
        const int n4o = D * D / 4;
        const int n4r = B * S / 4;
        const int tot = n4x + n4q + n4o + n4r;
        cvt_all<<<(tot + 255) / 256, 256, 0, stream>>>(x, w_qkv, w_out, xb, wqb, wob,
                                                      rsum, n4x, n4q, n4o, n4r);
    }

    // 2) QKV = x @ Wqkv^T + b  [16384, 2304]; V third written TRANSPOSED to vt
    gemm_nt_bf16<unsigned short, false, false, true><<<dim3(3 * D / 128, MS / 128, 1), 256, 0, stream>>>(
        xb, D, 0, wqb, D, 0, qkvb, 3 * D, 0, b_qkv, 1.0f, D, nullptr, nullptr, vt);

    // 3) att = exp(scale * Q @ K^T) per batch [1024,1024]; rowsum via atomics
    const float scale = 0.03608439182435162f;  // 1/sqrt(768)
    gemm_nt_bf16<unsigned short, true, false, false><<<dim3(S / 128, S / 128, B), 256, 0, stream>>>(
        qkvb,     3 * D, (long long)S * 3 * D,
        qkvb + D, 3 * D, (long long)S * 3 * D,
        att, S, (long long)S * S, nullptr, scale, D, rsum, nullptr, nullptr);

    // 4) O = (P~ @ V) * 1/rowsum per row   per batch [1024, 768]
    gemm_nt_bf16<unsigned short, false, true, false><<<dim3(D / 128, S / 128, B), 256, 0, stream>>>(
        att, S, (long long)S * S,
        vt,  S, (long long)D * S,
        ob,  D, (long long)S * D, nullptr, 1.0f, S, nullptr, rsum, nullptr);

    // 5) out = O @ Wout^T + b   [16384, 768] fp32
    gemm_nt_bf16<float, false, false, false><<<dim3(D / 128, MS / 128, 1), 256, 0, stream>>>(
        ob, D, 0, wob, D, 0, out, D, 0, b_out, 1.0f, D, nullptr, nullptr, nullptr);
}

// Round 5
// 279.147 us; speedup vs baseline: 1.1931x; 1.0521x over previous
//
#include <hip/hip_runtime.h>
#include <hip/hip_bf16.h>
#include <math.h>

// ---------- types ----------
typedef __attribute__((ext_vector_type(8))) short bf16x8;   // 8 bf16 in 4 VGPRs
typedef __attribute__((ext_vector_type(4))) float f32x4;

// ---------- helpers ----------
__device__ __forceinline__ unsigned short f2bf_rne(float f) {
    union { float f; unsigned u; } x; x.f = f;
    unsigned r = x.u + 0x7FFFu + ((x.u >> 16) & 1u);
    return (unsigned short)(r >> 16);
}
__device__ __forceinline__ float bf2f(unsigned short u) {
    union { unsigned u; float f; } x; x.u = ((unsigned)u) << 16; return x.f;
}

// 4 consecutive elements per lane (transposed-MFMA epilogue): 8B bf16 / 16B f32
__device__ __forceinline__ void store4(unsigned short* p, float v0, float v1, float v2, float v3) {
    ushort4 o; o.x = f2bf_rne(v0); o.y = f2bf_rne(v1); o.z = f2bf_rne(v2); o.w = f2bf_rne(v3);
    *(ushort4*)p = o;          // 8 B store, gn0 % 4 == 0 -> aligned
}
__device__ __forceinline__ void store4(float* p, float v0, float v1, float v2, float v3) {
    float4 o; o.x = v0; o.y = v1; o.z = v2; o.w = v3;
    *(float4*)p = o;           // 16 B store
}

__device__ __forceinline__ void async_copy16(const void* g, void* l) {
    __builtin_amdgcn_global_load_lds(
        (const __attribute__((address_space(1))) void*)g,
        (__attribute__((address_space(3))) void*)l, 16, 0, 0);
}

// ---------- fused fp32 -> bf16 converts + workspace zeroing (one launch) ----------
// ranges: x->xb, w_out->wob, zero z1 (rsum|v1|v2 contiguous), zero z2 (B2 pad rows)
__global__ __launch_bounds__(256) void cvt_all(
    const float* __restrict__ x, const float* __restrict__ wo,
    unsigned short* __restrict__ xb, unsigned short* __restrict__ wob,
    float4* __restrict__ z1, float4* __restrict__ z2,
    int n4x, int n4o, int n4r, int n4z)
{
    int j = blockIdx.x * 256 + threadIdx.x;
    const float* in; unsigned short* out;
    if (j < n4x) { in = x; out = xb; }
    else {
        j -= n4x;
        if (j < n4o) { in = wo; out = wob; }
        else {
            j -= n4o;
            if (j < n4r) { float4 z = {0.f, 0.f, 0.f, 0.f}; z1[j] = z; return; }
            j -= n4r;
            if (j < n4z) { float4 z = {0.f, 0.f, 0.f, 0.f}; z2[j] = z; }
            return;
        }
    }
    float4 v = ((const float4*)in)[j];
    ushort4 o;
    o.x = f2bf_rne(v.x); o.y = f2bf_rne(v.y);
    o.z = f2bf_rne(v.z); o.w = f2bf_rne(v.w);
    ((ushort4*)out)[j] = o;
}

// ---------- prep: weight transposes + small reductions (one launch) ----------
// blocks 0..431:   64x64-tile transposes of Wq/Wk/Wv (fp32 [o][i] -> bf16 [i][o]);
//                  Wq tiles also accumulate v1[i] += sum_o Wq[o,i]*bk[o] (atomics),
//                  Wk tiles accumulate v2[i] += sum_o Wk[o,i]*bq[o].
// blocks 432..623: b''[d] = b_out[d] + sum_o Wout[d,o]*bv[o]   (wave per row)
// block  624:      c = bq . bk
__global__ __launch_bounds__(256) void prep(
    const float* __restrict__ w_qkv, const float* __restrict__ b_qkv,
    const float* __restrict__ w_out, const float* __restrict__ b_out,
    unsigned short* __restrict__ wqT, unsigned short* __restrict__ wkT,
    unsigned short* __restrict__ wvT,
    float* __restrict__ v1f, float* __restrict__ v2f,
    float* __restrict__ bpp, float* __restrict__ cbuf)
{
    const int blk = blockIdx.x;
    const int t   = threadIdx.x;
    if (blk < 432) {
        __shared__ float sh[64][65];     // +1 pad: conflict-free transpose
        __shared__ float pv[4][64];
        const int m  = blk / 144;        // matrix 0=Wq 1=Wk 2=Wv
        const int r  = blk % 144;
        const int ty = r / 12;           // o-tile
        const int tx = r % 12;           // i-tile
        const float* W = w_qkv + (long long)m * 768 * 768;
        unsigned short* WT = (m == 0) ? wqT : (m == 1) ? wkT : wvT;
        const float* bsrc = (m == 0) ? (b_qkv + 768) : b_qkv;  // bk for Wq, bq for Wk
        const int il = t & 63;
        const int ob = t >> 6;
        float acc = 0.f;
#pragma unroll
        for (int it = 0; it < 16; ++it) {
            const int ol = ob + it * 4;
            float w = W[(long long)(ty * 64 + ol) * 768 + tx * 64 + il];
            sh[ol][il] = w;
            if (m < 2) acc += w * bsrc[ty * 64 + ol];
        }
        __syncthreads();
#pragma unroll
        for (int it = 0; it < 16; ++it) {
            const int il2 = ob + it * 4;
            WT[(long long)(tx * 64 + il2) * 768 + ty * 64 + il] = f2bf_rne(sh[il][il2]);
        }
        if (m < 2) {
            pv[ob][il] = acc;
            __syncthreads();
            if (t < 64) {
                float s = pv[0][t] + pv[1][t] + pv[2][t] + pv[3][t];
                atomicAdd((m == 0 ? v1f : v2f) + tx * 64 + t, s);
            }
        }
    } else if (blk < 624) {
        const int d = (blk - 432) * 4 + (t >> 6);
        const int l = t & 63;
        float s = 0.f;
        for (int o = l; o < 768; o += 64)
            s += w_out[(long long)d * 768 + o] * b_qkv[1536 + o];
        for (int off = 1; off < 64; off <<= 1) s += __shfl_xor(s, off);
        if (l == 0) bpp[d] = b_out[d] + s;
    } else {
        if (t < 64) {
            float s = 0.f;
            for (int o = t; o < 768; o += 64) s += b_qkv[o] * b_qkv[768 + o];
            for (int off = 1; off < 64; off <<= 1) s += __shfl_xor(s, off);
            if (t == 0) cbuf[0] = s;
        }
    }
}

// ---------- finishprep: v1,v2 (fp32 atomato totals) -> B2 rows 1536,1537 (bf16) ----------
__global__ __launch_bounds__(256) void finishprep(
    const float* __restrict__ v1f, const float* __restrict__ v2f,
    unsigned short* __restrict__ B2)
{
    int i = blockIdx.x * 256 + threadIdx.x;
    if (i < 768) {
        B2[1536LL * 768 + i] = f2bf_rne(v1f[i]);
        B2[1537LL * 768 + i] = f2bf_rne(v2f[i]);
    }
}

// ---------- NT bf16 GEMM: C[m,n] = f( scale * sum_k A[m,k]*B[n,k] ) + bias[n] ----------
// R0-proven structure: 128x128 tile, BK=64, 256 threads = 4 waves (2x2), 64x64 per wave.
// R1-R3 post-mortems: every source-level async variant regressed (toolchain drains
// LDS-DMA at phase boundaries); keep the 2-barrier loop. DO NOT re-add pipelining.
// XCD-chunked block swizzle kept (R3/R4 verified: QKV FETCH_SIZE 124->59 MB).
// LDS XOR-swizzled 16B granules (SQ_LDS_BANK_CONFLICT=0). MFMA operands swapped
// (D = C^T fragment) -> contiguous stores.
//
// Epilogue fusions (R5 algebra-fold pipeline):
//   DO_EXP:    att = exp(scale*(acc + u[q] + w[k] + c)); u,w read from A's extra
//              columns K+768/K+769 (the xm buffer carries u=x.v1, w=x.v2);
//              c read from rscale[0]. atomicAdd per-row exp-sums into rowsum[].
//   DO_RSCALE: multiply row m by scale/rowsum[m] and add bias (final out, fp32).
//   DO_VT:     blocks with tileN in [768,1536) write vt[b][d][k] transposed
//              (the VW=x@W'^T third of the combined x-GEMM).
template <typename OutT, bool DO_EXP, bool DO_RSCALE, bool DO_VT>
__global__ __launch_bounds__(256) void gemm_nt_bf16(
    const unsigned short* __restrict__ A, int lda, long long strideA,
    const unsigned short* __restrict__ B, int ldb, long long strideB,
    OutT* __restrict__ C, int ldc, long long strideC,
    const float* __restrict__ bias, float scale, int K,
    float* __restrict__ rowsum, const float* __restrict__ rscale,
    unsigned short* __restrict__ vtp)
{
    __shared__ unsigned short shA[128 * 64];
    __shared__ unsigned short shB[128 * 64];

    const int t    = threadIdx.x;
    const int lane = t & 63;
    const int wave = t >> 6;
    const int wm   = (wave & 1) * 64;   // wave row offset in tile
    const int wn   = (wave >> 1) * 64;  // wave col offset in tile
    const int quad = lane >> 4;
    const int l16  = lane & 15;

    // ---- XCD-chunked block swizzle (all launch grids are %8 == 0) ----
    const int gx = gridDim.x, gy = gridDim.y;
    const int nwg = gx * gy * gridDim.z;
    const int orig = blockIdx.x + gx * (blockIdx.y + gy * blockIdx.z);
    const int id  = (orig & 7) * (nwg >> 3) + (orig >> 3);
    const int bx  = id % gx;
    const int rem = id / gx;
    const int by  = rem % gy;
    const int bz  = rem / gy;

    const long long batch = bz;
    A += batch * strideA;
    B += batch * strideB;
    C += batch * strideC;

    const long long tileM = (long long)by * 128;
    const long long tileN = (long long)bx * 128;
    const long long rowsPerBatch = (long long)gy * 128;

    f32x4 acc[4][4];
#pragma unroll
    for (int i = 0; i < 4; ++i)
#pragma unroll
        for (int j = 0; j < 4; ++j)
#pragma unroll
            for (int r = 0; r < 4; ++r) acc[i][j][r] = 0.0f;

    for (int k0 = 0; k0 < K; k0 += 64) {
        __syncthreads();   // previous iter's frags consumed before overwrite
#pragma unroll
        for (int p = 0; p < 4; ++p) {
            const int g   = p * 256 + t;        // LDS granule 0..1023 (lane-ordered)
            const int row = g >> 3;             // 0..127
            const int kg  = (g & 7) ^ (row & 7);// swizzled source k-granule
            async_copy16(A + (tileM + row) * (long long)lda + k0 + kg * 8, &shA[g << 3]);
            async_copy16(B + (tileN + row) * (long long)ldb + k0 + kg * 8, &shB[g << 3]);
        }
        __syncthreads();   // compiler drains vmcnt(0) before barrier

#pragma unroll 1           // keep only one K-half's fragments live (VGPR cap)
        for (int h = 0; h < 2; ++h) {
            bf16x8 af[4], bfr[4];
#pragma unroll
            for (int mi = 0; mi < 4; ++mi) {
                const int row = wm + mi * 16 + l16;
                const int kg  = ((h << 2) | quad) ^ (row & 7);
                af[mi] = *(const bf16x8*)(&shA[row * 64 + kg * 8]);
            }
#pragma unroll
            for (int ni = 0; ni < 4; ++ni) {
                const int row = wn + ni * 16 + l16;
                const int kg  = ((h << 2) | quad) ^ (row & 7);
                bfr[ni] = *(const bf16x8*)(&shB[row * 64 + kg * 8]);
            }
#pragma unroll
            for (int mi = 0; mi < 4; ++mi)
#pragma unroll
                for (int ni = 0; ni < 4; ++ni)
                    acc[mi][ni] = __builtin_amdgcn_mfma_f32_16x16x32_bf16(
                        bfr[ni], af[mi], acc[mi][ni], 0, 0, 0);   // operands swapped: D = C^T frag
        }
    }

    // epilogue: D holds C^T tile: lane -> m = l16 (fixed row), n = quad*4 + {0..3}
    const bool vt_block = DO_VT && (tileN >= 768) && (tileN < 1536);
    float cadd = 0.f;
    if (DO_EXP) cadd = rscale[0];           // c = bq.bk (device-computed)
#pragma unroll
    for (int mi = 0; mi < 4; ++mi) {
        const long long gm = tileM + wm + mi * 16 + l16;
        float w = scale;
        if (DO_RSCALE) w = scale / rscale[batch * rowsPerBatch + gm];
        float uq = 0.f;
        if (DO_EXP) uq = bf2f(A[gm * (long long)lda + K + 768]) + cadd;  // u[q] + c
        float rsum = 0.0f;
#pragma unroll
        for (int ni = 0; ni < 4; ++ni) {
            const long long gn0 = tileN + wn + ni * 16 + quad * 4;
            float b0 = 0.f, b1 = 0.f, b2 = 0.f, b3 = 0.f;
            if (bias) {
                float4 bv = *(const float4*)&bias[gn0];
                b0 = bv.x; b1 = bv.y; b2 = bv.z; b3 = bv.w;
            }
            const f32x4 a = acc[mi][ni];
            float v0, v1, v2, v3;
            if (DO_EXP) {
                // w[k] from xm column K+769 (bf16), k = gn0..gn0+3
                const float w0 = bf2f(A[(gn0 + 0) * (long long)lda + K + 769]);
                const float w1 = bf2f(A[(gn0 + 1) * (long long)lda + K + 769]);
                const float w2 = bf2f(A[(gn0 + 2) * (long long)lda + K + 769]);
                const float w3 = bf2f(A[(gn0 + 3) * (long long)lda + K + 769]);
                v0 = __expf((a[0] + uq + w0) * scale);
                v1 = __expf((a[1] + uq + w1) * scale);
                v2 = __expf((a[2] + uq + w2) * scale);
                v3 = __expf((a[3] + uq + w3) * scale);
                rsum += (v0 + v1) + (v2 + v3);
            } else {
                v0 = a[0] * w + b0; v1 = a[1] * w + b1;
                v2 = a[2] * w + b2; v3 = a[3] * w + b3;
            }
            if (vt_block) {
                // vt[b][d][k]: d = gn0-768+r, b = gm>>10, k = gm&1023
                const long long b_i  = gm >> 10;
                const long long kin  = gm & 1023;
                unsigned short* vp = vtp + (b_i * 768 + (gn0 - 768)) * 1024 + kin;
                vp[0]        = f2bf_rne(v0);
                vp[1024]     = f2bf_rne(v1);
                vp[2 * 1024] = f2bf_rne(v2);
                vp[3 * 1024] = f2bf_rne(v3);
            } else {
                store4(C + gm * (long long)ldc + gn0, v0, v1, v2, v3);
            }
        }
        if (DO_EXP) {
            // lanes sharing l16 (quad bits = lane bits 4,5) hold disjoint n-ranges
            rsum += __shfl_xor(rsum, 16);
            rsum += __shfl_xor(rsum, 32);
            if (quad == 0)
                atomicAdd(&rowsum[batch * rowsPerBatch + gm], rsum);
        }
    }
}

// ---------- launcher ----------
// R5 pipeline (weight-algebra fold; 93 GFLOP vs R4's 129):
//   out = softmax(scale*(x M x^T + u1^T + 1w^T + c)) @ (x W'^T) + b''
//   M = Wq^T Wk, W' = Wout Wv, v1 = Wq^T bk, v2 = Wk^T bq, c = bq.bk,
//   b'' = b_out + Wout bv  (V-bias passes through the row-stochastic softmax).
extern "C" void kernel_launch(void* const* d_in, const int* in_sizes, int n_in,
                              void* d_out, int out_size, void* d_ws, size_t ws_size,
                              hipStream_t stream) {
    (void)in_sizes; (void)n_in; (void)out_size; (void)ws_size;

    const float* x     = (const float*)d_in[0];
    const float* w_qkv = (const float*)d_in[1];
    const float* b_qkv = (const float*)d_in[2];
    const float* w_out = (const float*)d_in[3];
    const float* b_out = (const float*)d_in[4];
    float* out = (float*)d_out;

    const int B = 16, S = 1024, D = 768;
    const long long MS = (long long)B * S;  // 16384 rows
    const int NB2 = 1664;                   // B2 rows: M^T (768) | W' (768) | v1,v2 | pad to 13*128

    // workspace layout (bf16 = ushort), all 16B aligned
    unsigned short* xb  = (unsigned short*)d_ws;           // [16384][768]
    unsigned short* wob = xb  + MS * D;                    // [768][768]   Wout bf16
    unsigned short* wqT = wob + (long long)D * D;          // [768][768]   Wq^T bf16
    unsigned short* wkT = wqT + (long long)D * D;          // Wk^T
    unsigned short* wvT = wkT + (long long)D * D;          // Wv^T
    unsigned short* B2  = wvT + (long long)D * D;          // [1664][768]
    unsigned short* xm  = B2  + (long long)NB2 * D;        // [16384][1664]
    unsigned short* vwt = xm  + MS * NB2;                  // [16][768][1024]  (x W'^T)^T
    unsigned short* att = vwt + (long long)B * D * S;      // [16][1024][1024] exp(logits)
    float* rsum = (float*)(att + (long long)B * S * S);    // [16384]
    float* v1f  = rsum + MS;                               // [768]
    float* v2f  = v1f + D;                                 // [768]
    float* bpp  = v2f + D;                                 // [768]  b''
    float* cbuf = bpp + D;                                 // [4]

    // 1) converts + zeroing (rsum|v1|v2 contiguous; B2 pad rows 1538..1663)
    {
        const int n4x = (int)(MS * D / 4);
        const int n4o = D * D / 4;
        const int n4r = (int)((MS + 2 * D) / 4);
        const int n4z = (NB2 - 1538) * D * 2 / 16;
        const int tot = n4x + n4o + n4r + n4z;
        cvt_all<<<(tot + 255) / 256, 256, 0, stream>>>(
            x, w_out, xb, wob, (float4*)rsum, (float4*)(B2 + 1538LL * D),
            n4x, n4o, n4r, n4z);
    }

    // 2) prep: Wq^T/Wk^T/Wv^T transposes + v1,v2 atomics + b'' + c
    prep<<<625, 256, 0, stream>>>(w_qkv, b_qkv, w_out, b_out,
                                  wqT, wkT, wvT, v1f, v2f, bpp, cbuf);

    // 3) v1,v2 -> B2 rows 1536,1537 (bf16)
    finishprep<<<3, 256, 0, stream>>>(v1f, v2f, B2);

    // 4) batched 768^3 GEMM: z=0: B2[0:768] = M^T = (Wk^T)·(Wq^T)^T ;
    //                        z=1: B2[768:1536] = W' = Wout·(Wv^T)^T
    gemm_nt_bf16<unsigned short, false, false, false><<<dim3(6, 6, 2), 256, 0, stream>>>(
        wkT, D, (long long)(wob - wkT),
        wqT, D, (long long)(wvT - wqT),
        B2,  D, (long long)D * D,
        nullptr, 1.0f, D, nullptr, nullptr, nullptr);

    // 5) combined x-GEMM: xm = x @ B2^T [16384,1664]
    //    cols 0..767 = x M (normal), 768..1535 = x W'^T -> vwt TRANSPOSED,
    //    cols 1536,1537 = u,w (normal into xm)
    gemm_nt_bf16<unsigned short, false, false, true><<<dim3(NB2 / 128, (int)(MS / 128), 1), 256, 0, stream>>>(
        xb, D, 0, B2, D, 0, xm, NB2, 0, nullptr, 1.0f, D, nullptr, nullptr, vwt);

    // 6) att = exp(scale*(xm @ x^T + u[q] + w[k] + c)) per batch; rowsum atomics
    const float scale = 0.03608439182435162f;  // 1/sqrt(768)
    gemm_nt_bf16<unsigned short, true, false, false><<<dim3(S / 128, S / 128, B), 256, 0, stream>>>(
        xm, NB2, (long long)S * NB2,
        xb, D,   (long long)S * D,
        att, S,  (long long)S * S, nullptr, scale, D, rsum, cbuf, nullptr);

    // 7) out = (att @ vwt^T) / rowsum + b''   [16384,768] fp32 (final)
    gemm_nt_bf16<float, false, true, false><<<dim3(D / 128, S / 128, B), 256, 0, stream>>>(
        att, S, (long long)S * S,
        vwt, S, (long long)D * S,
        out, D, (long long)S * D, bpp, 1.0f, S, nullptr, rsum, nullptr);
}

// Round 6
// 274.098 us; speedup vs baseline: 1.2151x; 1.0184x over previous
//
#include <hip/hip_runtime.h>
#include <hip/hip_bf16.h>
#include <math.h>

// ---------- types ----------
typedef __attribute__((ext_vector_type(8))) short bf16x8;   // 8 bf16 in 4 VGPRs
typedef __attribute__((ext_vector_type(4))) float f32x4;

// ---------- helpers ----------
__device__ __forceinline__ unsigned short f2bf_rne(float f) {
    union { float f; unsigned u; } x; x.f = f;
    unsigned r = x.u + 0x7FFFu + ((x.u >> 16) & 1u);
    return (unsigned short)(r >> 16);
}

// 4 consecutive elements per lane (transposed-MFMA epilogue): 8B bf16 / 16B f32
__device__ __forceinline__ void store4(unsigned short* p, float v0, float v1, float v2, float v3) {
    ushort4 o; o.x = f2bf_rne(v0); o.y = f2bf_rne(v1); o.z = f2bf_rne(v2); o.w = f2bf_rne(v3);
    *(ushort4*)p = o;          // 8 B store, gn0 % 4 == 0 -> aligned
}
__device__ __forceinline__ void store4(float* p, float v0, float v1, float v2, float v3) {
    float4 o; o.x = v0; o.y = v1; o.z = v2; o.w = v3;
    *(float4*)p = o;           // 16 B store
}

__device__ __forceinline__ void async_copy16(const void* g, void* l) {
    __builtin_amdgcn_global_load_lds(
        (const __attribute__((address_space(1))) void*)g,
        (__attribute__((address_space(3))) void*)l, 16, 0, 0);
}

// ---------- prep: weight transposes + small reductions + wob cvt + rsum zero ----------
// blocks 0..431:    64x64-tile transposes of Wq/Wk/Wv (fp32 [o][i] -> bf16 [i][o]);
//                   Wq/Wk tiles write per-(o-tile) partial dots into vpart (NO atomics,
//                   every slot written exactly once -> no pre-zeroing needed):
//                   vpart[(m*12+ty)*768 + i] = sum_{o in tile ty} W[o,i]*b[o].
// blocks 432..623:  b''[d] = b_out[d] + sum_o Wout[d,o]*bv[o]   (wave per row)
// block  624:       c = bq . bk
// blocks 625..1200: w_out fp32 -> wob bf16 (flat, 576*256 = 147456 float4 exact)
// blocks 1201..1216: zero rsum (16*256 = 4096 float4 exact)
__global__ __launch_bounds__(256) void prep(
    const float* __restrict__ w_qkv, const float* __restrict__ b_qkv,
    const float* __restrict__ w_out, const float* __restrict__ b_out,
    unsigned short* __restrict__ wqT, unsigned short* __restrict__ wkT,
    unsigned short* __restrict__ wvT, unsigned short* __restrict__ wob,
    float* __restrict__ vpart, float* __restrict__ bpp, float* __restrict__ cbuf,
    float* __restrict__ rsum)
{
    const int blk = blockIdx.x;
    const int t   = threadIdx.x;
    if (blk < 432) {
        __shared__ float sh[64][65];     // +1 pad: conflict-free transpose
        __shared__ float pv[4][64];
        const int m  = blk / 144;        // matrix 0=Wq 1=Wk 2=Wv
        const int r  = blk % 144;
        const int ty = r / 12;           // o-tile
        const int tx = r % 12;           // i-tile
        const float* W = w_qkv + (long long)m * 768 * 768;
        unsigned short* WT = (m == 0) ? wqT : (m == 1) ? wkT : wvT;
        const float* bsrc = (m == 0) ? (b_qkv + 768) : b_qkv;  // bk for Wq, bq for Wk
        const int il = t & 63;
        const int ob = t >> 6;
        float acc = 0.f;
#pragma unroll
        for (int it = 0; it < 16; ++it) {
            const int ol = ob + it * 4;
            float w = W[(long long)(ty * 64 + ol) * 768 + tx * 64 + il];
            sh[ol][il] = w;
            if (m < 2) acc += w * bsrc[ty * 64 + ol];
        }
        __syncthreads();
#pragma unroll
        for (int it = 0; it < 16; ++it) {
            const int il2 = ob + it * 4;
            WT[(long long)(tx * 64 + il2) * 768 + ty * 64 + il] = f2bf_rne(sh[il][il2]);
        }
        if (m < 2) {
            pv[ob][il] = acc;
            __syncthreads();
            if (t < 64) {
                float s = pv[0][t] + pv[1][t] + pv[2][t] + pv[3][t];
                vpart[(m * 12 + ty) * 768 + tx * 64 + t] = s;
            }
        }
    } else if (blk < 624) {
        const int d = (blk - 432) * 4 + (t >> 6);
        const int l = t & 63;
        float s = 0.f;
        for (int o = l; o < 768; o += 64)
            s += w_out[(long long)d * 768 + o] * b_qkv[1536 + o];
        for (int off = 1; off < 64; off <<= 1) s += __shfl_xor(s, off);
        if (l == 0) bpp[d] = b_out[d] + s;
    } else if (blk == 624) {
        if (t < 64) {
            float s = 0.f;
            for (int o = t; o < 768; o += 64) s += b_qkv[o] * b_qkv[768 + o];
            for (int off = 1; off < 64; off <<= 1) s += __shfl_xor(s, off);
            if (t == 0) cbuf[0] = s;
        }
    } else if (blk < 1201) {
        const int j = (blk - 625) * 256 + t;         // < 147456 exact
        float4 v = ((const float4*)w_out)[j];
        ushort4 o;
        o.x = f2bf_rne(v.x); o.y = f2bf_rne(v.y);
        o.z = f2bf_rne(v.z); o.w = f2bf_rne(v.w);
        ((ushort4*)wob)[j] = o;
    } else {
        const int j = (blk - 1201) * 256 + t;        // < 4096 exact
        float4 z = {0.f, 0.f, 0.f, 0.f};
        ((float4*)rsum)[j] = z;
    }
}

// ---------- finishv: reduce 12 o-tile partials -> v1,v2 fp32 ----------
__global__ __launch_bounds__(256) void finishv(
    const float* __restrict__ vpart, float* __restrict__ v1f, float* __restrict__ v2f)
{
    const int j = blockIdx.x * 256 + threadIdx.x;    // 0..1535 exact
    const int m = (j >= 768);
    const int i = j - m * 768;
    float s = 0.f;
#pragma unroll
    for (int ty = 0; ty < 12; ++ty) s += vpart[(m * 12 + ty) * 768 + i];
    (m ? v2f : v1f)[i] = s;
}

// ---------- cvt_x: x fp32 -> bf16, fused u = x.v1, w = x.v2 (wave per row) ----------
// Replaces the x-GEMM's u,w column-tile (was 128 blocks of GEMM for 2 useful cols).
__global__ __launch_bounds__(256) void cvt_x(
    const float* __restrict__ x, unsigned short* __restrict__ xb,
    const float* __restrict__ v1f, const float* __restrict__ v2f,
    float* __restrict__ uf, float* __restrict__ wf)
{
    const int wave = threadIdx.x >> 6;
    const int lane = threadIdx.x & 63;
    const long long row = (long long)blockIdx.x * 4 + wave;   // 16384 rows exact
    const float4* xr = (const float4*)x + row * 192;
    ushort4* xbr = (ushort4*)xb + row * 192;
    const float4* v1 = (const float4*)v1f;
    const float4* v2 = (const float4*)v2f;
    float u = 0.f, w = 0.f;
#pragma unroll
    for (int j = 0; j < 3; ++j) {
        const int c = j * 64 + lane;
        float4 v = xr[c];
        ushort4 o;
        o.x = f2bf_rne(v.x); o.y = f2bf_rne(v.y);
        o.z = f2bf_rne(v.z); o.w = f2bf_rne(v.w);
        xbr[c] = o;
        float4 a = v1[c], b = v2[c];
        u += v.x * a.x + v.y * a.y + v.z * a.z + v.w * a.w;
        w += v.x * b.x + v.y * b.y + v.z * b.z + v.w * b.w;
    }
#pragma unroll
    for (int off = 1; off < 64; off <<= 1) {
        u += __shfl_xor(u, off);
        w += __shfl_xor(w, off);
    }
    if (lane == 0) { uf[row] = u; wf[row] = w; }
}

// ---------- NT bf16 GEMM: C[m,n] = f( scale * sum_k A[m,k]*B[n,k] ) + bias[n] ----------
// R0-proven structure: 128x128 tile, BK=64, 256 threads = 4 waves (2x2), 64x64 per wave.
// R1-R3 post-mortems: every source-level async variant regressed (toolchain drains
// LDS-DMA at phase boundaries); keep the 2-barrier loop. DO NOT re-add pipelining.
// XCD-chunked block swizzle kept (R3/R4 verified: FETCH_SIZE halved on big GEMMs).
// LDS XOR-swizzled 16B granules (SQ_LDS_BANK_CONFLICT=0). MFMA operands swapped
// (D = C^T fragment) -> contiguous stores.
//
// Epilogue fusions:
//   DO_EXP:    att = exp(scale*(acc + u[q] + w[k] + c)); u,w from fp32 arrays uf/wf
//              (computed in cvt_x); c from rscale[0]. atomicAdd exp-sums -> rowsum[].
//   DO_RSCALE: multiply row m by scale/rowsum[m] and add bias (final out, fp32).
//   DO_VT:     blocks with tileN in [768,1536) write vt[b][d][k] transposed via an
//              LDS-staged coalesced path (R6): C^T tile re-staged d-major into
//              shA/shB (pitch 132, 2-way-max bank aliasing) post-K-loop, then
//              written as 8 B granules — replaces 64x 2 B scattered stores/lane
//              (R5 counters showed +8 MB write-assembly overhead from those).
template <typename OutT, bool DO_EXP, bool DO_RSCALE, bool DO_VT>
__global__ __launch_bounds__(256) void gemm_nt_bf16(
    const unsigned short* __restrict__ A, int lda, long long strideA,
    const unsigned short* __restrict__ B, int ldb, long long strideB,
    OutT* __restrict__ C, int ldc, long long strideC,
    const float* __restrict__ bias, float scale, int K,
    float* __restrict__ rowsum, const float* __restrict__ rscale,
    unsigned short* __restrict__ vtp,
    const float* __restrict__ uf, const float* __restrict__ wf)
{
    // 8448 = 64*132: K-loop uses first 8192 (128 rows x 64); vt epilogue re-uses
    // as [64][132] d-major tile halves (pitch 132 -> +2 banks/row, aligned 8 B).
    __shared__ unsigned short shA[8448];
    __shared__ unsigned short shB[8448];

    const int t    = threadIdx.x;
    const int lane = t & 63;
    const int wave = t >> 6;
    const int wm   = (wave & 1) * 64;   // wave row offset in tile
    const int wn   = (wave >> 1) * 64;  // wave col offset in tile
    const int quad = lane >> 4;
    const int l16  = lane & 15;

    // ---- XCD-chunked block swizzle (all launch grids are %8 == 0) ----
    const int gx = gridDim.x, gy = gridDim.y;
    const int nwg = gx * gy * gridDim.z;
    const int orig = blockIdx.x + gx * (blockIdx.y + gy * blockIdx.z);
    const int id  = (orig & 7) * (nwg >> 3) + (orig >> 3);
    const int bx  = id % gx;
    const int rem = id / gx;
    const int by  = rem % gy;
    const int bz  = rem / gy;

    const long long batch = bz;
    A += batch * strideA;
    B += batch * strideB;
    C += batch * strideC;

    const long long tileM = (long long)by * 128;
    const long long tileN = (long long)bx * 128;
    const long long rowsPerBatch = (long long)gy * 128;

    f32x4 acc[4][4];
#pragma unroll
    for (int i = 0; i < 4; ++i)
#pragma unroll
        for (int j = 0; j < 4; ++j)
#pragma unroll
            for (int r = 0; r < 4; ++r) acc[i][j][r] = 0.0f;

    for (int k0 = 0; k0 < K; k0 += 64) {
        __syncthreads();   // previous iter's frags consumed before overwrite
#pragma unroll
        for (int p = 0; p < 4; ++p) {
            const int g   = p * 256 + t;        // LDS granule 0..1023 (lane-ordered)
            const int row = g >> 3;             // 0..127
            const int kg  = (g & 7) ^ (row & 7);// swizzled source k-granule
            async_copy16(A + (tileM + row) * (long long)lda + k0 + kg * 8, &shA[g << 3]);
            async_copy16(B + (tileN + row) * (long long)ldb + k0 + kg * 8, &shB[g << 3]);
        }
        __syncthreads();   // compiler drains vmcnt(0) before barrier

#pragma unroll 1           // keep only one K-half's fragments live (VGPR cap)
        for (int h = 0; h < 2; ++h) {
            bf16x8 af[4], bfr[4];
#pragma unroll
            for (int mi = 0; mi < 4; ++mi) {
                const int row = wm + mi * 16 + l16;
                const int kg  = ((h << 2) | quad) ^ (row & 7);
                af[mi] = *(const bf16x8*)(&shA[row * 64 + kg * 8]);
            }
#pragma unroll
            for (int ni = 0; ni < 4; ++ni) {
                const int row = wn + ni * 16 + l16;
                const int kg  = ((h << 2) | quad) ^ (row & 7);
                bfr[ni] = *(const bf16x8*)(&shB[row * 64 + kg * 8]);
            }
#pragma unroll
            for (int mi = 0; mi < 4; ++mi)
#pragma unroll
                for (int ni = 0; ni < 4; ++ni)
                    acc[mi][ni] = __builtin_amdgcn_mfma_f32_16x16x32_bf16(
                        bfr[ni], af[mi], acc[mi][ni], 0, 0, 0);   // operands swapped: D = C^T frag
        }
    }

    // epilogue: D holds C^T tile: lane -> m = l16 (fixed row), n = quad*4 + {0..3}
    const bool vt_block = DO_VT && (tileN >= 768) && (tileN < 1536);
    if (vt_block) __syncthreads();          // all waves done reading shA/shB
    unsigned short* const shd = (wn == 0) ? shA : shB;   // d<64 -> shA, else shB
    float cadd = 0.f;
    if (DO_EXP) cadd = rscale[0];           // c = bq.bk (device-computed)
    const float* ufb = DO_EXP ? (uf + batch * rowsPerBatch) : nullptr;
    const float* wfb = DO_EXP ? (wf + batch * rowsPerBatch) : nullptr;
#pragma unroll
    for (int mi = 0; mi < 4; ++mi) {
        const long long gm = tileM + wm + mi * 16 + l16;
        float w = scale;
        if (DO_RSCALE) w = scale / rscale[batch * rowsPerBatch + gm];
        float uq = 0.f;
        if (DO_EXP) uq = ufb[gm] + cadd;    // u[q] + c
        float rsum = 0.0f;
#pragma unroll
        for (int ni = 0; ni < 4; ++ni) {
            const long long gn0 = tileN + wn + ni * 16 + quad * 4;
            float b0 = 0.f, b1 = 0.f, b2 = 0.f, b3 = 0.f;
            if (bias) {
                float4 bv = *(const float4*)&bias[gn0];
                b0 = bv.x; b1 = bv.y; b2 = bv.z; b3 = bv.w;
            }
            const f32x4 a = acc[mi][ni];
            float v0, v1, v2, v3;
            if (DO_EXP) {
                const float w0 = wfb[gn0 + 0];
                const float w1 = wfb[gn0 + 1];
                const float w2 = wfb[gn0 + 2];
                const float w3 = wfb[gn0 + 3];
                v0 = __expf((a[0] + uq + w0) * scale);
                v1 = __expf((a[1] + uq + w1) * scale);
                v2 = __expf((a[2] + uq + w2) * scale);
                v3 = __expf((a[3] + uq + w3) * scale);
                rsum += (v0 + v1) + (v2 + v3);
            } else {
                v0 = a[0] * w + b0; v1 = a[1] * w + b1;
                v2 = a[2] * w + b2; v3 = a[3] * w + b3;
            }
            if (vt_block) {
                // stage into d-major LDS tile: row = local d (0..63), col = local k
                const int dl = ni * 16 + quad * 4;            // local d (within half)
                const int kl = wm + mi * 16 + l16;            // local k (0..127)
                shd[(dl + 0) * 132 + kl] = f2bf_rne(v0);
                shd[(dl + 1) * 132 + kl] = f2bf_rne(v1);
                shd[(dl + 2) * 132 + kl] = f2bf_rne(v2);
                shd[(dl + 3) * 132 + kl] = f2bf_rne(v3);
            } else {
                store4(C + gm * (long long)ldc + gn0, v0, v1, v2, v3);
            }
        }
        if (DO_EXP) {
            // lanes sharing l16 (quad bits = lane bits 4,5) hold disjoint n-ranges
            rsum += __shfl_xor(rsum, 16);
            rsum += __shfl_xor(rsum, 32);
            if (quad == 0)
                atomicAdd(&rowsum[batch * rowsPerBatch + gm], rsum);
        }
    }
    if (vt_block) {
        __syncthreads();
        // cooperative coalesced write: 2 threads per d-row, 8 B granules
        const long long bvt  = tileM >> 10;          // batch (128 | 1024)
        const long long kin0 = tileM & 1023;
        const int dr = t >> 1;                       // 0..127
        const int hf = t & 1;                        // k-half
        const unsigned short* src = (dr < 64) ? &shA[dr * 132] : &shB[(dr - 64) * 132];
        unsigned short* dst = vtp + (bvt * 768 + (tileN - 768) + dr) * 1024 + kin0 + hf * 64;
        src += hf * 64;
#pragma unroll
        for (int j = 0; j < 16; ++j)
            *(uint2*)(dst + j * 4) = *(const uint2*)(src + j * 4);
    }
}

// ---------- launcher ----------
// R6 pipeline (weight-algebra fold, u/w fused into cvt):
//   out = softmax(scale*(x M x^T + u1^T + 1w^T + c)) @ (x W'^T) + b''
//   M = Wq^T Wk, W' = Wout Wv, u = x(Wq^T bk), w = x(Wk^T bq), c = bq.bk,
//   b'' = b_out + Wout bv  (V-bias passes through the row-stochastic softmax).
extern "C" void kernel_launch(void* const* d_in, const int* in_sizes, int n_in,
                              void* d_out, int out_size, void* d_ws, size_t ws_size,
                              hipStream_t stream) {
    (void)in_sizes; (void)n_in; (void)out_size; (void)ws_size;

    const float* x     = (const float*)d_in[0];
    const float* w_qkv = (const float*)d_in[1];
    const float* b_qkv = (const float*)d_in[2];
    const float* w_out = (const float*)d_in[3];
    const float* b_out = (const float*)d_in[4];
    float* out = (float*)d_out;

    const int B = 16, S = 1024, D = 768;
    const long long MS = (long long)B * S;  // 16384 rows
    const int NB2 = 1536;                   // B2 rows: M^T (768) | W' (768)

    // workspace layout (bf16 = ushort), all 16B aligned
    unsigned short* xb  = (unsigned short*)d_ws;           // [16384][768]
    unsigned short* wob = xb  + MS * D;                    // [768][768]   Wout bf16
    unsigned short* wqT = wob + (long long)D * D;          // [768][768]   Wq^T bf16
    unsigned short* wkT = wqT + (long long)D * D;          // Wk^T
    unsigned short* wvT = wkT + (long long)D * D;          // Wv^T
    unsigned short* B2  = wvT + (long long)D * D;          // [1536][768]
    unsigned short* xm  = B2  + (long long)NB2 * D;        // [16384][1536]
    unsigned short* vwt = xm  + MS * NB2;                  // [16][768][1024]  (x W'^T)^T
    unsigned short* att = vwt + (long long)B * D * S;      // [16][1024][1024] exp(logits)
    float* rsum  = (float*)(att + (long long)B * S * S);   // [16384]
    float* v1f   = rsum + MS;                              // [768]
    float* v2f   = v1f + D;                                // [768]
    float* bpp   = v2f + D;                                // [768]  b''
    float* cbuf  = bpp + D;                                // [4]
    float* uf    = cbuf + 4;                               // [16384]
    float* wf    = uf + MS;                                // [16384]
    float* vpart = wf + MS;                                // [2*12*768]

    // 1) prep: Wq^T/Wk^T/Wv^T transposes + v-partials + b'' + c + wob cvt + rsum zero
    prep<<<1217, 256, 0, stream>>>(w_qkv, b_qkv, w_out, b_out,
                                   wqT, wkT, wvT, wob, vpart, bpp, cbuf, rsum);

    // 2) finishv: v1 = Wq^T bk, v2 = Wk^T bq (fp32)
    finishv<<<6, 256, 0, stream>>>(vpart, v1f, v2f);

    // 3) batched 768^3 GEMM: z=0: B2[0:768] = M^T = (Wk^T)·(Wq^T)^T ;
    //                        z=1: B2[768:1536] = W' = Wout·(Wv^T)^T
    gemm_nt_bf16<unsigned short, false, false, false><<<dim3(6, 6, 2), 256, 0, stream>>>(
        wkT, D, (long long)(wob - wkT),
        wqT, D, (long long)(wvT - wqT),
        B2,  D, (long long)D * D,
        nullptr, 1.0f, D, nullptr, nullptr, nullptr, nullptr, nullptr);

    // 4) cvt_x: x -> xb bf16, fused u = x.v1, w = x.v2 (fp32)
    cvt_x<<<4096, 256, 0, stream>>>(x, xb, v1f, v2f, uf, wf);

    // 5) combined x-GEMM: xm = x @ B2^T [16384,1536]
    //    cols 0..767 = x M (normal), 768..1535 = x W'^T -> vwt TRANSPOSED (LDS-staged)
    gemm_nt_bf16<unsigned short, false, false, true><<<dim3(NB2 / 128, (int)(MS / 128), 1), 256, 0, stream>>>(
        xb, D, 0, B2, D, 0, xm, NB2, 0, nullptr, 1.0f, D, nullptr, nullptr, vwt, nullptr, nullptr);

    // 6) att = exp(scale*(xm @ x^T + u[q] + w[k] + c)) per batch; rowsum atomics
    const float scale = 0.03608439182435162f;  // 1/sqrt(768)
    gemm_nt_bf16<unsigned short, true, false, false><<<dim3(S / 128, S / 128, B), 256, 0, stream>>>(
        xm, NB2, (long long)S * NB2,
        xb, D,   (long long)S * D,
        att, S,  (long long)S * S, nullptr, scale, D, rsum, cbuf, nullptr, uf, wf);

    // 7) out = (att @ vwt^T) / rowsum + b''   [16384,768] fp32 (final)
    gemm_nt_bf16<float, false, true, false><<<dim3(D / 128, S / 128, B), 256, 0, stream>>>(
        att, S, (long long)S * S,
        vwt, S, (long long)D * S,
        out, D, (long long)S * D, bpp, 1.0f, S, nullptr, rsum, nullptr, nullptr, nullptr);
}

// Round 7
// 259.772 us; speedup vs baseline: 1.2821x; 1.0551x over previous
//
#include <hip/hip_runtime.h>
#include <hip/hip_bf16.h>
#include <math.h>

// ---------- types ----------
typedef __attribute__((ext_vector_type(8))) short bf16x8;   // 8 bf16 in 4 VGPRs
typedef __attribute__((ext_vector_type(4))) float f32x4;

// ---------- helpers ----------
__device__ __forceinline__ unsigned short f2bf_rne(float f) {
    union { float f; unsigned u; } x; x.f = f;
    unsigned r = x.u + 0x7FFFu + ((x.u >> 16) & 1u);
    return (unsigned short)(r >> 16);
}

// 4 consecutive elements per lane (transposed-MFMA epilogue): 8B bf16 / 16B f32
__device__ __forceinline__ void store4(unsigned short* p, float v0, float v1, float v2, float v3) {
    ushort4 o; o.x = f2bf_rne(v0); o.y = f2bf_rne(v1); o.z = f2bf_rne(v2); o.w = f2bf_rne(v3);
    *(ushort4*)p = o;          // 8 B store, gn0 % 4 == 0 -> aligned
}
__device__ __forceinline__ void store4(float* p, float v0, float v1, float v2, float v3) {
    float4 o; o.x = v0; o.y = v1; o.z = v2; o.w = v3;
    *(float4*)p = o;           // 16 B store
}

__device__ __forceinline__ void async_copy16(const void* g, void* l) {
    __builtin_amdgcn_global_load_lds(
        (const __attribute__((address_space(1))) void*)g,
        (__attribute__((address_space(3))) void*)l, 16, 0, 0);
}

// ---------- shared 128x128 GEMM core (R0-proven 2-barrier loop) ----------
// R1-R3 post-mortems: every source-level async variant regressed (toolchain drains
// LDS-DMA at phase boundaries); keep the 2-barrier loop. DO NOT re-add pipelining.
// LDS XOR-swizzled 16B granules (SQ_LDS_BANK_CONFLICT=0). MFMA operands swapped
// (D = B-frag x A-frag = C^T fragment) -> contiguous stores in epilogues.
__device__ __forceinline__ void gemm_core128(
    unsigned short* shA, unsigned short* shB,
    const unsigned short* __restrict__ A, int lda,
    const unsigned short* __restrict__ B, int ldb,
    long long tileM, long long tileN, int K,
    int t, int wm, int wn, int quad, int l16, f32x4 (&acc)[4][4])
{
    for (int k0 = 0; k0 < K; k0 += 64) {
        __syncthreads();   // previous iter's frags consumed before overwrite
#pragma unroll
        for (int p = 0; p < 4; ++p) {
            const int g   = p * 256 + t;        // LDS granule 0..1023 (lane-ordered)
            const int row = g >> 3;             // 0..127
            const int kg  = (g & 7) ^ (row & 7);// swizzled source k-granule
            async_copy16(A + (tileM + row) * (long long)lda + k0 + kg * 8, &shA[g << 3]);
            async_copy16(B + (tileN + row) * (long long)ldb + k0 + kg * 8, &shB[g << 3]);
        }
        __syncthreads();   // compiler drains vmcnt(0) before barrier

#pragma unroll 1           // keep only one K-half's fragments live (VGPR cap)
        for (int h = 0; h < 2; ++h) {
            bf16x8 af[4], bfr[4];
#pragma unroll
            for (int mi = 0; mi < 4; ++mi) {
                const int row = wm + mi * 16 + l16;
                const int kg  = ((h << 2) | quad) ^ (row & 7);
                af[mi] = *(const bf16x8*)(&shA[row * 64 + kg * 8]);
            }
#pragma unroll
            for (int ni = 0; ni < 4; ++ni) {
                const int row = wn + ni * 16 + l16;
                const int kg  = ((h << 2) | quad) ^ (row & 7);
                bfr[ni] = *(const bf16x8*)(&shB[row * 64 + kg * 8]);
            }
#pragma unroll
            for (int mi = 0; mi < 4; ++mi)
#pragma unroll
                for (int ni = 0; ni < 4; ++ni)
                    acc[mi][ni] = __builtin_amdgcn_mfma_f32_16x16x32_bf16(
                        bfr[ni], af[mi], acc[mi][ni], 0, 0, 0);   // swapped: C^T frag
        }
    }
}

// ---------- prep: weight transposes + v2 atomics + b'' + wob cvt ----------
// R7: u = x.(Wq^T bk) and c = bq.bk are DELETED — softmax is shift-invariant per
// row, so per-q constants cancel exactly in att/rowsum. Only w = x.(Wk^T bq)
// (per-k term) survives.
// blocks 0..431:    64x64-tile transposes of Wq/Wk/Wv (fp32 [o][i] -> bf16 [i][o]);
//                   Wk tiles atomicAdd v2 partials (v2f zeroed by hipMemsetAsync).
// blocks 432..623:  b''[d] = b_out[d] + sum_o Wout[d,o]*bv[o]   (wave per row)
// blocks 624..1199: w_out fp32 -> wob bf16 (flat, 576*256 = 147456 float4 exact)
__global__ __launch_bounds__(256) void prep(
    const float* __restrict__ w_qkv, const float* __restrict__ b_qkv,
    const float* __restrict__ w_out, const float* __restrict__ b_out,
    unsigned short* __restrict__ wqT, unsigned short* __restrict__ wkT,
    unsigned short* __restrict__ wvT, unsigned short* __restrict__ wob,
    float* __restrict__ v2f, float* __restrict__ bpp)
{
    const int blk = blockIdx.x;
    const int t   = threadIdx.x;
    if (blk < 432) {
        __shared__ float sh[64][65];     // +1 pad: conflict-free transpose
        __shared__ float pv[4][64];
        const int m  = blk / 144;        // matrix 0=Wq 1=Wk 2=Wv
        const int r  = blk % 144;
        const int ty = r / 12;           // o-tile
        const int tx = r % 12;           // i-tile
        const float* W = w_qkv + (long long)m * 768 * 768;
        unsigned short* WT = (m == 0) ? wqT : (m == 1) ? wkT : wvT;
        const int il = t & 63;
        const int ob = t >> 6;
        float acc = 0.f;
#pragma unroll
        for (int it = 0; it < 16; ++it) {
            const int ol = ob + it * 4;
            float w = W[(long long)(ty * 64 + ol) * 768 + tx * 64 + il];
            sh[ol][il] = w;
            if (m == 1) acc += w * b_qkv[ty * 64 + ol];   // Wk^T bq partial
        }
        __syncthreads();
#pragma unroll
        for (int it = 0; it < 16; ++it) {
            const int il2 = ob + it * 4;
            WT[(long long)(tx * 64 + il2) * 768 + ty * 64 + il] = f2bf_rne(sh[il][il2]);
        }
        if (m == 1) {
            pv[ob][il] = acc;
            __syncthreads();
            if (t < 64)
                atomicAdd(&v2f[tx * 64 + t], pv[0][t] + pv[1][t] + pv[2][t] + pv[3][t]);
        }
    } else if (blk < 624) {
        const int d = (blk - 432) * 4 + (t >> 6);
        const int l = t & 63;
        float s = 0.f;
        for (int o = l; o < 768; o += 64)
            s += w_out[(long long)d * 768 + o] * b_qkv[1536 + o];
        for (int off = 1; off < 64; off <<= 1) s += __shfl_xor(s, off);
        if (l == 0) bpp[d] = b_out[d] + s;
    } else {
        const int j = (blk - 624) * 256 + t;         // < 147456 exact
        float4 v = ((const float4*)w_out)[j];
        ushort4 o;
        o.x = f2bf_rne(v.x); o.y = f2bf_rne(v.y);
        o.z = f2bf_rne(v.z); o.w = f2bf_rne(v.w);
        ((ushort4*)wob)[j] = o;
    }
}

// ---------- wgemm_cvt: weight GEMMs (72 blocks) || x convert + w dot (4096 blocks) ----------
// R7 merge: the 2.4-GFLOP weight GEMM (72 blocks = 28% of one CU-round if launched
// alone) hides entirely under the BW-bound x-convert. Both depend only on prep.
// blocks 0..71:   z=blk/36: z=0: B2[0:768] = M^T = (Wk^T)·(Wq^T)^T
//                           z=1: B2[768:1536] = W' = Wout·(Wv^T)^T
// blocks 72..4167: per wave one x row: xb = bf16(x), wf[row] = x . v2
__global__ __launch_bounds__(256) void wgemm_cvt(
    const unsigned short* __restrict__ wkT, const unsigned short* __restrict__ wqT,
    const unsigned short* __restrict__ wob, const unsigned short* __restrict__ wvT,
    unsigned short* __restrict__ B2,
    const float* __restrict__ x, unsigned short* __restrict__ xb,
    const float* __restrict__ v2f, float* __restrict__ wf)
{
    const int t = threadIdx.x;
    if (blockIdx.x < 72) {
        __shared__ unsigned short shA[8192];
        __shared__ unsigned short shB[8192];
        const int lane = t & 63;
        const int wave = t >> 6;
        const int wm   = (wave & 1) * 64;
        const int wn   = (wave >> 1) * 64;
        const int quad = lane >> 4;
        const int l16  = lane & 15;
        const int z  = blockIdx.x / 36;
        const int r  = blockIdx.x % 36;
        const long long tileM = (long long)(r / 6) * 128;
        const long long tileN = (long long)(r % 6) * 128;
        const unsigned short* A  = z ? wob : wkT;
        const unsigned short* Bp = z ? wvT : wqT;
        unsigned short* C = B2 + (long long)z * 768 * 768;

        f32x4 acc[4][4];
#pragma unroll
        for (int i = 0; i < 4; ++i)
#pragma unroll
            for (int j = 0; j < 4; ++j)
#pragma unroll
                for (int rr = 0; rr < 4; ++rr) acc[i][j][rr] = 0.0f;

        gemm_core128(shA, shB, A, 768, Bp, 768, tileM, tileN, 768,
                     t, wm, wn, quad, l16, acc);

#pragma unroll
        for (int mi = 0; mi < 4; ++mi) {
            const long long gm = tileM + wm + mi * 16 + l16;
#pragma unroll
            for (int ni = 0; ni < 4; ++ni) {
                const long long gn0 = tileN + wn + ni * 16 + quad * 4;
                const f32x4 a = acc[mi][ni];
                store4(C + gm * 768 + gn0, a[0], a[1], a[2], a[3]);
            }
        }
    } else {
        const int wave = t >> 6;
        const int lane = t & 63;
        const long long row = (long long)(blockIdx.x - 72) * 4 + wave;  // 16384 exact
        const float4* xr = (const float4*)x + row * 192;
        ushort4* xbr = (ushort4*)xb + row * 192;
        const float4* v2 = (const float4*)v2f;
        float w = 0.f;
#pragma unroll
        for (int j = 0; j < 3; ++j) {
            const int c = j * 64 + lane;
            float4 v = xr[c];
            ushort4 o;
            o.x = f2bf_rne(v.x); o.y = f2bf_rne(v.y);
            o.z = f2bf_rne(v.z); o.w = f2bf_rne(v.w);
            xbr[c] = o;
            float4 b = v2[c];
            w += v.x * b.x + v.y * b.y + v.z * b.z + v.w * b.w;
        }
#pragma unroll
        for (int off = 1; off < 64; off <<= 1) w += __shfl_xor(w, off);
        if (lane == 0) wf[row] = w;
    }
}

// ---------- NT bf16 GEMM: C[m,n] = f( scale * sum_k A[m,k]*B[n,k] ) + bias[n] ----------
// R0-proven structure (gemm_core128). XCD-chunked block swizzle kept (R3/R4
// verified: FETCH_SIZE halved on big GEMMs).
//
// Epilogue fusions:
//   DO_EXP:    att = exp(scale*(acc + w[k])); w from fp32 array wf (computed in
//              wgemm_cvt); per-q constants u,c dropped (softmax shift-invariance).
//              atomicAdd exp-sums -> rowsum[].
//   DO_RSCALE: multiply row m by scale/rowsum[m] and add bias (final out, fp32).
//   DO_VT:     blocks with tileN in [768,1536) write vt[b][d][k] transposed via
//              LDS-staged coalesced path (R6: replaces 64x 2B scattered stores).
template <typename OutT, bool DO_EXP, bool DO_RSCALE, bool DO_VT>
__global__ __launch_bounds__(256) void gemm_nt_bf16(
    const unsigned short* __restrict__ A, int lda, long long strideA,
    const unsigned short* __restrict__ B, int ldb, long long strideB,
    OutT* __restrict__ C, int ldc, long long strideC,
    const float* __restrict__ bias, float scale, int K,
    float* __restrict__ rowsum, const float* __restrict__ rscale,
    unsigned short* __restrict__ vtp, const float* __restrict__ wf)
{
    // 8448 = 64*132: K-loop uses first 8192 (128 rows x 64); vt epilogue re-uses
    // as [64][132] d-major tile halves (pitch 132 -> 2-way-max bank aliasing).
    __shared__ unsigned short shA[8448];
    __shared__ unsigned short shB[8448];

    const int t    = threadIdx.x;
    const int lane = t & 63;
    const int wave = t >> 6;
    const int wm   = (wave & 1) * 64;   // wave row offset in tile
    const int wn   = (wave >> 1) * 64;  // wave col offset in tile
    const int quad = lane >> 4;
    const int l16  = lane & 15;

    // ---- XCD-chunked block swizzle (all launch grids are %8 == 0) ----
    const int gx = gridDim.x, gy = gridDim.y;
    const int nwg = gx * gy * gridDim.z;
    const int orig = blockIdx.x + gx * (blockIdx.y + gy * blockIdx.z);
    const int id  = (orig & 7) * (nwg >> 3) + (orig >> 3);
    const int bx  = id % gx;
    const int rem = id / gx;
    const int by  = rem % gy;
    const int bz  = rem / gy;

    const long long batch = bz;
    A += batch * strideA;
    B += batch * strideB;
    C += batch * strideC;

    const long long tileM = (long long)by * 128;
    const long long tileN = (long long)bx * 128;
    const long long rowsPerBatch = (long long)gy * 128;

    f32x4 acc[4][4];
#pragma unroll
    for (int i = 0; i < 4; ++i)
#pragma unroll
        for (int j = 0; j < 4; ++j)
#pragma unroll
            for (int r = 0; r < 4; ++r) acc[i][j][r] = 0.0f;

    gemm_core128(shA, shB, A, lda, B, ldb, tileM, tileN, K, t, wm, wn, quad, l16, acc);

    // epilogue: D holds C^T tile: lane -> m = l16 (fixed row), n = quad*4 + {0..3}
    const bool vt_block = DO_VT && (tileN >= 768) && (tileN < 1536);
    if (vt_block) __syncthreads();          // all waves done reading shA/shB
    unsigned short* const shd = (wn == 0) ? shA : shB;   // d<64 -> shA, else shB

    // hoist per-k softmax shift w[k] (mi-invariant): one aligned float4 per ni
    float wkv[4][4];
    if (DO_EXP) {
        const float* wfb = wf + batch * rowsPerBatch;
#pragma unroll
        for (int ni = 0; ni < 4; ++ni) {
            const long long gn0 = tileN + wn + ni * 16 + quad * 4;
            float4 t4 = *(const float4*)&wfb[gn0];
            wkv[ni][0] = t4.x; wkv[ni][1] = t4.y; wkv[ni][2] = t4.z; wkv[ni][3] = t4.w;
        }
    }
#pragma unroll
    for (int mi = 0; mi < 4; ++mi) {
        const long long gm = tileM + wm + mi * 16 + l16;
        float w = scale;
        if (DO_RSCALE) w = scale / rscale[batch * rowsPerBatch + gm];
        float rsum = 0.0f;
#pragma unroll
        for (int ni = 0; ni < 4; ++ni) {
            const long long gn0 = tileN + wn + ni * 16 + quad * 4;
            float b0 = 0.f, b1 = 0.f, b2 = 0.f, b3 = 0.f;
            if (bias) {
                float4 bv = *(const float4*)&bias[gn0];
                b0 = bv.x; b1 = bv.y; b2 = bv.z; b3 = bv.w;
            }
            const f32x4 a = acc[mi][ni];
            float v0, v1, v2, v3;
            if (DO_EXP) {
                v0 = __expf((a[0] + wkv[ni][0]) * scale);
                v1 = __expf((a[1] + wkv[ni][1]) * scale);
                v2 = __expf((a[2] + wkv[ni][2]) * scale);
                v3 = __expf((a[3] + wkv[ni][3]) * scale);
                rsum += (v0 + v1) + (v2 + v3);
            } else {
                v0 = a[0] * w + b0; v1 = a[1] * w + b1;
                v2 = a[2] * w + b2; v3 = a[3] * w + b3;
            }
            if (vt_block) {
                // stage into d-major LDS tile: row = local d (0..63), col = local k
                const int dl = ni * 16 + quad * 4;            // local d (within half)
                const int kl = wm + mi * 16 + l16;            // local k (0..127)
                shd[(dl + 0) * 132 + kl] = f2bf_rne(v0);
                shd[(dl + 1) * 132 + kl] = f2bf_rne(v1);
                shd[(dl + 2) * 132 + kl] = f2bf_rne(v2);
                shd[(dl + 3) * 132 + kl] = f2bf_rne(v3);
            } else {
                store4(C + gm * (long long)ldc + gn0, v0, v1, v2, v3);
            }
        }
        if (DO_EXP) {
            // lanes sharing l16 (quad bits = lane bits 4,5) hold disjoint n-ranges
            rsum += __shfl_xor(rsum, 16);
            rsum += __shfl_xor(rsum, 32);
            if (quad == 0)
                atomicAdd(&rowsum[batch * rowsPerBatch + gm], rsum);
        }
    }
    if (vt_block) {
        __syncthreads();
        // cooperative coalesced write: 2 threads per d-row, 8 B granules
        const long long bvt  = tileM >> 10;          // batch
        const long long kin0 = tileM & 1023;
        const int dr = t >> 1;                       // 0..127
        const int hf = t & 1;                        // k-half
        const unsigned short* src = (dr < 64) ? &shA[dr * 132] : &shB[(dr - 64) * 132];
        unsigned short* dst = vtp + (bvt * 768 + (tileN - 768) + dr) * 1024 + kin0 + hf * 64;
        src += hf * 64;
#pragma unroll
        for (int j = 0; j < 16; ++j)
            *(uint2*)(dst + j * 4) = *(const uint2*)(src + j * 4);
    }
}

// ---------- launcher ----------
// R7 pipeline (u/c dropped by softmax shift-invariance; W-GEMM hidden under cvt):
//   att = exp(scale*(x M x^T + 1w^T)),  out = (att @ (x W'^T)) / rowsum + b''
//   M = Wq^T Wk, W' = Wout Wv, w = x(Wk^T bq), b'' = b_out + Wout bv.
extern "C" void kernel_launch(void* const* d_in, const int* in_sizes, int n_in,
                              void* d_out, int out_size, void* d_ws, size_t ws_size,
                              hipStream_t stream) {
    (void)in_sizes; (void)n_in; (void)out_size; (void)ws_size;

    const float* x     = (const float*)d_in[0];
    const float* w_qkv = (const float*)d_in[1];
    const float* b_qkv = (const float*)d_in[2];
    const float* w_out = (const float*)d_in[3];
    const float* b_out = (const float*)d_in[4];
    float* out = (float*)d_out;

    const int B = 16, S = 1024, D = 768;
    const long long MS = (long long)B * S;  // 16384 rows
    const int NB2 = 1536;                   // B2 rows: M^T (768) | W' (768)

    // workspace layout (bf16 = ushort), all 16B aligned
    unsigned short* xb  = (unsigned short*)d_ws;           // [16384][768]
    unsigned short* wob = xb  + MS * D;                    // [768][768]   Wout bf16
    unsigned short* wqT = wob + (long long)D * D;          // [768][768]   Wq^T bf16
    unsigned short* wkT = wqT + (long long)D * D;          // Wk^T
    unsigned short* wvT = wkT + (long long)D * D;          // Wv^T
    unsigned short* B2  = wvT + (long long)D * D;          // [1536][768]
    unsigned short* xm  = B2  + (long long)NB2 * D;        // [16384][1536]
    unsigned short* vwt = xm  + MS * NB2;                  // [16][768][1024]  (x W'^T)^T
    unsigned short* att = vwt + (long long)B * D * S;      // [16][1024][1024] exp(logits)
    float* rsum = (float*)(att + (long long)B * S * S);    // [16384]   (zeroed by memset)
    float* v2f  = rsum + MS;                               // [768]     (zeroed by memset)
    float* bpp  = v2f + D;                                 // [768]  b''
    float* wf   = bpp + D;                                 // [16384]

    // 1) zero rsum|v2f in one memset (contiguous)
    hipMemsetAsync(rsum, 0, (size_t)(MS + D) * sizeof(float), stream);

    // 2) prep: Wq^T/Wk^T/Wv^T transposes + v2 atomics + b'' + wob cvt
    prep<<<1200, 256, 0, stream>>>(w_qkv, b_qkv, w_out, b_out,
                                   wqT, wkT, wvT, wob, v2f, bpp);

    // 3) merged: weight GEMMs (72 blocks, hidden) || x->bf16 + w = x.v2 (4096 blocks)
    wgemm_cvt<<<4168, 256, 0, stream>>>(wkT, wqT, wob, wvT, B2, x, xb, v2f, wf);

    // 4) combined x-GEMM: xm = x @ B2^T [16384,1536]
    //    cols 0..767 = x M (normal), 768..1535 = x W'^T -> vwt TRANSPOSED (LDS-staged)
    gemm_nt_bf16<unsigned short, false, false, true><<<dim3(NB2 / 128, (int)(MS / 128), 1), 256, 0, stream>>>(
        xb, D, 0, B2, D, 0, xm, NB2, 0, nullptr, 1.0f, D, nullptr, nullptr, vwt, nullptr);

    // 5) att = exp(scale*(xm @ x^T + w[k])) per batch; rowsum atomics
    const float scale = 0.03608439182435162f;  // 1/sqrt(768)
    gemm_nt_bf16<unsigned short, true, false, false><<<dim3(S / 128, S / 128, B), 256, 0, stream>>>(
        xm, NB2, (long long)S * NB2,
        xb, D,   (long long)S * D,
        att, S,  (long long)S * S, nullptr, scale, D, rsum, nullptr, nullptr, wf);

    // 6) out = (att @ vwt^T) / rowsum + b''   [16384,768] fp32 (final)
    gemm_nt_bf16<float, false, true, false><<<dim3(D / 128, S / 128, B), 256, 0, stream>>>(
        att, S, (long long)S * S,
        vwt, S, (long long)D * S,
        out, D, (long long)S * D, bpp, 1.0f, S, nullptr, rsum, nullptr, nullptr);
}